// Round 2
// baseline (344.938 us; speedup 1.0000x reference)
//
#include <hip/hip_runtime.h>
#include <hip/hip_bf16.h>
#include <math.h>

#define S_LEN 4096
#define EMB   1024
#define E3    3072
#define NH    16
#define HD    64

// flash partial-combine geometry: qi<=10 direct; qi 11..21 -> 2 chunks;
// qi 22..31 -> 3 chunks.  52 partial slots per head, 832 total.
#define SLOTS_PER_HEAD 52
#define NSLOTS         832

typedef unsigned short u16;
typedef short          bfrag __attribute__((ext_vector_type(8)));  // 8 bf16
typedef float          ffrag __attribute__((ext_vector_type(4)));  // 4 f32
typedef unsigned short us8   __attribute__((ext_vector_type(8)));
typedef unsigned short us4   __attribute__((ext_vector_type(4)));

__device__ __forceinline__ u16 f2bf(float f) {
    union { float f; unsigned u; } v; v.f = f;
    unsigned r = v.u + 0x7fffu + ((v.u >> 16) & 1u);
    return (u16)(r >> 16);
}
__device__ __forceinline__ float bf2f(u16 b) {
    union { unsigned u; float f; } v; v.u = ((unsigned)b) << 16;
    return v.f;
}
// pack two f32 -> two bf16 (truncation) in one v_perm_b32
__device__ __forceinline__ unsigned pack_bf16_trunc(float lo, float hi) {
    union { float f; unsigned u; } a, b; a.f = lo; b.f = hi;
    return __builtin_amdgcn_perm(b.u, a.u, 0x07060302u);
}
// async global->LDS, 16B per lane; LDS dest = uniform base + lane*16
__device__ __forceinline__ void gld16(const void* g, void* l) {
    __builtin_amdgcn_global_load_lds(
        (const __attribute__((address_space(1))) unsigned int*)g,
        (__attribute__((address_space(3))) unsigned int*)l, 16, 0, 0);
}

// ---------------------------------------------------------------------------
// RoPE cos/sin table: tab[s][j] = (cos, sin)(s * 10000^(-j/32)), j < 32.
// 1 MB; aliases ctxb (dead until flash writes it).  Same sincosf as the old
// gemm epilogue -> bit-identical values.
// ---------------------------------------------------------------------------
__global__ __launch_bounds__(256)
void rope_tab_kernel(float2* __restrict__ tab) {
    const int idx = blockIdx.x * 256 + threadIdx.x;   // s*32 + j
    const int s = idx >> 5, j = idx & 31;
    const float C = 13.287712379549449f / 32.0f;      // log2(10000)/32
    const float invf = exp2f(-(float)j * C);
    float sn, cs;
    sincosf((float)s * invf, &sn, &cs);
    tab[idx] = make_float2(cs, sn);
}

// ---------------------------------------------------------------------------
// cast fp32 -> bf16, 8 elems/thread
// ---------------------------------------------------------------------------
__global__ __launch_bounds__(256)
void cast_bf16_kernel(const float* __restrict__ in, u16* __restrict__ out) {
    const size_t i = ((size_t)blockIdx.x * 256 + threadIdx.x) * 8;
    float4 a = *(const float4*)(in + i);
    float4 b = *(const float4*)(in + i + 4);
    us8 o;
    o[0]=f2bf(a.x); o[1]=f2bf(a.y); o[2]=f2bf(a.z); o[3]=f2bf(a.w);
    o[4]=f2bf(b.x); o[5]=f2bf(b.y); o[6]=f2bf(b.z); o[7]=f2bf(b.w);
    *(us8*)(out + i) = o;
}

// ---------------------------------------------------------------------------
// transpose+cast: in [R][C] fp32 -> out [C][R] bf16.  64x64 tiles.
// ---------------------------------------------------------------------------
__global__ __launch_bounds__(256)
void transpose_cast_kernel(const float* __restrict__ in, u16* __restrict__ out,
                           int R, int C) {
    __shared__ u16 T[64][72];
    const int r0 = blockIdx.x * 64, c0 = blockIdx.y * 64;
    const int t = threadIdx.x;
    const int rr = t >> 2, cc = (t & 3) * 16;

    const float* ip = in + (size_t)(r0 + rr) * C + c0 + cc;
    u16 tmp[16];
    #pragma unroll
    for (int i4 = 0; i4 < 4; i4++) {
        float4 v = ((const float4*)ip)[i4];
        tmp[4*i4+0]=f2bf(v.x); tmp[4*i4+1]=f2bf(v.y);
        tmp[4*i4+2]=f2bf(v.z); tmp[4*i4+3]=f2bf(v.w);
    }
    #pragma unroll
    for (int i8 = 0; i8 < 2; i8++) {
        us8 vv;
        #pragma unroll
        for (int j = 0; j < 8; j++) vv[j] = tmp[8*i8+j];
        *(us8*)&T[rr][cc + 8*i8] = vv;
    }
    __syncthreads();

    const int oc = t >> 2, orr = (t & 3) * 16;
    u16 ot[16];
    #pragma unroll
    for (int j = 0; j < 16; j++) ot[j] = T[orr + j][oc];
    u16* op = out + (size_t)(c0 + oc) * R + r0 + orr;
    #pragma unroll
    for (int i8 = 0; i8 < 2; i8++) {
        us8 vv;
        #pragma unroll
        for (int j = 0; j < 8; j++) vv[j] = ot[8*i8+j];
        *(us8*)(op + 8*i8) = vv;
    }
}

// ---------------------------------------------------------------------------
// bf16 MFMA GEMM, double-buffered: C[M,N] = A[M,K] * Bt[N,K]^T + bias
// Tile 128 x (32*NT); 4 waves as 2m x 2n; wave does 4x NT 16x16x32 tiles.
// ROPE=1 (requires NT=4):
//   n0 <  2048 : fuse RoPE rotation (+0.125*log2e scale for q) -> Cv (qkvb)
//                cos/sin from precomputed table (rope)
//   n0 >= 2048 : V region -- write bias-added values TRANSPOSED to vtp[d][s]
// ---------------------------------------------------------------------------
template <int OUT_BF16, int NT, int ROPE, int MINW>
__global__ __launch_bounds__(256, MINW)
void gemm_bt_kernel(const u16* __restrict__ A, const u16* __restrict__ Bt,
                    const float* __restrict__ bias, void* __restrict__ Cv,
                    u16* __restrict__ vtp, const float2* __restrict__ rope,
                    int M, int N, int K) {
    constexpr int BN = 32 * NT;       // block n-span
    constexpr int WS = 16 * NT;       // wave n-span
    __shared__ u16 As[2][128][32];
    __shared__ u16 Bs[2][BN][32];

    const int tid = threadIdx.x;
    const int w = tid >> 6, L = tid & 63;
    const int col = L & 15, quad = L >> 4;
    const int wm = w & 1, wn = w >> 1;
    const int m0 = blockIdx.x * 128, n0 = blockIdx.y * BN;

    ffrag acc[4][NT];
    #pragma unroll
    for (int a = 0; a < 4; a++)
        #pragma unroll
        for (int b = 0; b < NT; b++)
            #pragma unroll
            for (int r = 0; r < 4; r++) acc[a][b][r] = 0.f;

    const int srow = L >> 2;
    const int schk = L & 3;

    // prologue: stage k=0 into buf 0
    #pragma unroll
    for (int t = 0; t < 2; t++) {
        const int rg = (2 * w + t) * 16;
        gld16(A + (size_t)(m0 + rg + srow) * K + schk * 8, &As[0][rg][0]);
    }
    #pragma unroll
    for (int t = 0; t < NT / 2; t++) {
        const int rg = (w * (NT / 2) + t) * 16;
        gld16(Bt + (size_t)(n0 + rg + srow) * K + schk * 8, &Bs[0][rg][0]);
    }
    __syncthreads();

    int buf = 0;
    for (int k0 = 0; k0 < K; k0 += 32, buf ^= 1) {
        if (k0 + 32 < K) {
            #pragma unroll
            for (int t = 0; t < 2; t++) {
                const int rg = (2 * w + t) * 16;
                gld16(A + (size_t)(m0 + rg + srow) * K + k0 + 32 + schk * 8,
                      &As[buf ^ 1][rg][0]);
            }
            #pragma unroll
            for (int t = 0; t < NT / 2; t++) {
                const int rg = (w * (NT / 2) + t) * 16;
                gld16(Bt + (size_t)(n0 + rg + srow) * K + k0 + 32 + schk * 8,
                      &Bs[buf ^ 1][rg][0]);
            }
        }

        bfrag af[4], bf[NT];
        #pragma unroll
        for (int mt = 0; mt < 4; mt++)
            af[mt] = *(const bfrag*)&As[buf][64 * wm + 16 * mt + col][8 * quad];
        #pragma unroll
        for (int nt = 0; nt < NT; nt++)
            bf[nt] = *(const bfrag*)&Bs[buf][WS * wn + 16 * nt + col][8 * quad];
        #pragma unroll
        for (int mt = 0; mt < 4; mt++)
            #pragma unroll
            for (int nt = 0; nt < NT; nt++)
                acc[mt][nt] = __builtin_amdgcn_mfma_f32_16x16x32_bf16(
                    af[mt], bf[nt], acc[mt][nt], 0, 0, 0);

        __syncthreads();
    }

    float bv[NT];
    #pragma unroll
    for (int nt = 0; nt < NT; nt++) bv[nt] = bias[n0 + WS * wn + 16 * nt + col];

    if (ROPE && n0 < 2 * EMB) {
        // q (n<1024) or k (1024..2047): rotate (d, d+32) pairs, table lookup.
        const float SCq = (n0 < EMB) ? 0.125f * 1.44269504088896f : 1.0f;
        #pragma unroll
        for (int mt = 0; mt < 4; mt++) {
            #pragma unroll
            for (int r = 0; r < 4; r++) {
                const int mrow = m0 + 64 * wm + 16 * mt + 4 * quad + r;
                u16* cp = (u16*)Cv + (size_t)mrow * N + n0 + 64 * wn + col;
                #pragma unroll
                for (int pr = 0; pr < 2; pr++) {
                    const float2 t = rope[(size_t)mrow * 32 + col + 16 * pr];
                    const float cs = t.x, sn = t.y;
                    const float t1 = acc[mt][pr][r] + bv[pr];
                    const float t2 = acc[mt][pr + 2][r] + bv[pr + 2];
                    cp[16 * pr]      = f2bf((t1 * cs - t2 * sn) * SCq);
                    cp[16 * pr + 32] = f2bf((t2 * cs + t1 * sn) * SCq);
                }
            }
        }
    } else if (ROPE) {
        // V region: write transposed to vtp[d][s], d = n - 2048.
        #pragma unroll
        for (int nt = 0; nt < NT; nt++) {
            const int dg = n0 - 2 * EMB + WS * wn + 16 * nt + col;
            #pragma unroll
            for (int mt = 0; mt < 4; mt++) {
                const int s0 = m0 + 64 * wm + 16 * mt + 4 * quad;
                us4 pk;
                #pragma unroll
                for (int r = 0; r < 4; r++) pk[r] = f2bf(acc[mt][nt][r] + bv[nt]);
                *(us4*)&vtp[(size_t)dg * S_LEN + s0] = pk;
            }
        }
    } else {
        #pragma unroll
        for (int mt = 0; mt < 4; mt++) {
            #pragma unroll
            for (int r = 0; r < 4; r++) {
                const int m = m0 + 64 * wm + 16 * mt + 4 * quad + r;
                #pragma unroll
                for (int nt = 0; nt < NT; nt++) {
                    const int n = n0 + WS * wn + 16 * nt + col;
                    const float val = acc[mt][nt][r] + bv[nt];
                    if (OUT_BF16) ((u16*)Cv)[(size_t)m * N + n] = f2bf(val);
                    else          ((float*)Cv)[(size_t)m * N + n] = val;
                }
            }
        }
    }
}

// ---------------------------------------------------------------------------
// flash11: flash10 schedule, V read direct from L2 (no LDS staging).
// Per-XCD V working set = 2 heads x 64x4096 bf16 = 1 MB -> L2-resident;
// staging it through LDS was pure overhead (guide common-mistake #7).
// LDS drops 48->32 KB -> 4 blocks/CU (launch_bounds(256,4); VGPR ~100<=128).
// V fragments are loaded into registers at tile start, BEFORE the K
// global_load_lds prefetch, so the vmcnt wait for V leaves K in flight.
// ks=0 fragments load at tile top, ks=1 after QK^T (register-pressure split).
// Schedule (unchanged from flash10): qi<=10 direct; qi 11..21 2 chunks;
// qi 22..31 3 chunks; 1008 blocks, all resident at 4/CU.
// ---------------------------------------------------------------------------
__global__ __launch_bounds__(256, 4)
void flash11_kernel(const u16* __restrict__ qkvb, const u16* __restrict__ vt,
                    u16* __restrict__ ctxb, u16* __restrict__ pO,
                    float* __restrict__ pL) {
    __shared__ u16 QP[4][32][64];     // per-wave: Q rows, then P overlay
    __shared__ u16 Ks[2][64][64];

    const int id = blockIdx.x;                    // 0..1007
    const int x  = id & 7;                        // XCD
    const int tt = id >> 3;                       // 0..125
    const int h  = x + 8 * (tt & 1);              // 2 heads per XCD, interleaved
    const int o  = tt >> 1;                       // 0..62 order index, long-first

    int qi, ch, nc;
    if (o < 30)      { qi = 31 - o / 3;        ch = o % 3;        nc = 3; }
    else if (o < 33) { qi = 10 - (o - 30);     ch = 0;            nc = 1; }
    else if (o < 55) { const int oo = o - 33;  qi = 21 - oo / 2;  ch = oo & 1; nc = 2; }
    else             { qi = 7 - (o - 55);      ch = 0;            nc = 1; }

    const int total = 2 * qi + 2;
    const int Lc    = (total + nc - 1) / nc;
    const int kt0   = ch * Lc;
    const int cnt   = min(Lc, total - kt0);
    const bool lastch = (kt0 + cnt == total);     // chunk holding the diagonal
    const int q0 = qi * 128;

    const int tid = threadIdx.x;
    const int w = tid >> 6, L = tid & 63;
    const int col = L & 15, quad = L >> 4;
    const int lr = L >> 3, lp = L & 7;
    const int lc = lp ^ lr;                       // swizzled chunk for staging

    const bool domask = lastch;
    const int nwt = cnt - ((domask && w < 2) ? 1 : 0);

    const size_t kArow = (size_t)(16 * w + lr) * E3 + EMB + h * HD + lc * 8;
    const size_t kt0off  = (size_t)kt0 * 64 * E3;
    // per-lane V base: row (h*64 + col), key offset kt0*64 + 8*quad
    const u16* vbase = vt + (size_t)(h * HD + col) * S_LEN
                          + (size_t)kt0 * 64 + 8 * quad;

    // ---- stage Q (own wave's 32 rows) + K tile kt0 ----
    #pragma unroll
    for (int u = 0; u < 4; u++)
        gld16(qkvb + (size_t)(q0 + 32 * w + 8 * u + lr) * E3 + h * HD + lc * 8,
              &QP[w][8 * u][0]);
    #pragma unroll
    for (int u = 0; u < 2; u++)
        gld16(qkvb + kArow + kt0off + (size_t)(8 * u) * E3,
              &Ks[0][16 * w + 8 * u][0]);
    __syncthreads();

    bfrag qf[2][2];
    #pragma unroll
    for (int i = 0; i < 2; i++)
        #pragma unroll
        for (int ks = 0; ks < 2; ks++)
            qf[i][ks] = *(const bfrag*)
                ((const char*)&QP[w][16 * i + col][0] +
                 16 * ((4 * ks + quad) ^ (col & 7)));

    bfrag ones;
    #pragma unroll
    for (int i = 0; i < 8; i++) ones[i] = (short)0x3F80;

    ffrag o_[4][2], ol[2];
    #pragma unroll
    for (int d4 = 0; d4 < 4; d4++)
        #pragma unroll
        for (int i = 0; i < 2; i++)
            #pragma unroll
            for (int r2 = 0; r2 < 4; r2++) o_[d4][i][r2] = 0.f;
    #pragma unroll
    for (int i = 0; i < 2; i++)
        #pragma unroll
        for (int r2 = 0; r2 < 4; r2++) ol[i][r2] = 0.f;

    #pragma unroll 1
    for (int t = 0; t < cnt; t++) {
        const int buf = t & 1;

        // ---- V fragments, ks=0: direct global (L2), issued first so the
        //      vmcnt wait for them leaves the K prefetch in flight ----
        bfrag vA[4];
        #pragma unroll
        for (int d4 = 0; d4 < 4; d4++)
            vA[d4] = *(const bfrag*)(vbase + (size_t)(16 * d4) * S_LEN + t * 64);

        // prefetch next K tile into the other buffer (before compute)
        if (t + 1 < cnt) {
            const size_t ko = kArow + kt0off + (size_t)(t + 1) * 64 * E3;
            #pragma unroll
            for (int u = 0; u < 2; u++)
                gld16(qkvb + ko + (size_t)(8 * u) * E3,
                      &Ks[buf ^ 1][16 * w + 8 * u][0]);
        }

        if (t < nwt) {
            // ---- S^T = K Q^T ----
            ffrag st[4][2];
            #pragma unroll
            for (int t4 = 0; t4 < 4; t4++)
                #pragma unroll
                for (int i = 0; i < 2; i++)
                    #pragma unroll
                    for (int r2 = 0; r2 < 4; r2++) st[t4][i][r2] = 0.f;
            #pragma unroll
            for (int ks = 0; ks < 2; ks++) {
                bfrag kf[4];
                #pragma unroll
                for (int t4 = 0; t4 < 4; t4++)
                    kf[t4] = *(const bfrag*)
                        &Ks[buf][16 * t4 + col][(((4 * ks + quad) ^ (col & 7)) * 8)];
                #pragma unroll
                for (int t4 = 0; t4 < 4; t4++)
                    #pragma unroll
                    for (int i = 0; i < 2; i++)
                        st[t4][i] = __builtin_amdgcn_mfma_f32_16x16x32_bf16(
                            kf[t4], qf[i][ks], st[t4][i], 0, 0, 0);
            }

            // ---- V fragments, ks=1 (issued while softmax runs) ----
            bfrag vB[4];
            #pragma unroll
            for (int d4 = 0; d4 < 4; d4++)
                vB[d4] = *(const bfrag*)
                    (vbase + (size_t)(16 * d4) * S_LEN + t * 64 + 32);

            // ---- causal mask: only this wave's diagonal tile ----
            if (domask && t == nwt - 1) {
                #pragma unroll
                for (int i = 0; i < 2; i++) {
                    const int qrel = 32 * (w & 1) + 16 * i + col;
                    #pragma unroll
                    for (int t4 = 0; t4 < 4; t4++) {
                        const int key0 = 16 * t4 + 4 * quad;
                        #pragma unroll
                        for (int r2 = 0; r2 < 4; r2++)
                            if (key0 + r2 > qrel) st[t4][i][r2] = -3.0e38f;
                    }
                }
            }

            // ---- softmax numerator: p = exp2(s), no shift ----
            #pragma unroll
            for (int i = 0; i < 2; i++) {
                const int prow = 16 * i + col;
                #pragma unroll
                for (int t4 = 0; t4 < 4; t4++) {
                    float pr[4];
                    #pragma unroll
                    for (int r2 = 0; r2 < 4; r2++) pr[r2] = exp2f(st[t4][i][r2]);
                    uint2 pk;
                    pk.x = pack_bf16_trunc(pr[0], pr[1]);
                    pk.y = pack_bf16_trunc(pr[2], pr[3]);
                    const int c2 = (2 * t4 + (quad >> 1)) ^ (col & 7);
                    *(uint2*)((char*)&QP[w][prow][0] + 16 * c2 + 8 * (quad & 1)) = pk;
                }
            }

            // ---- O^T += V^T P^T ;  l += 1^T P^T ----
            #pragma unroll
            for (int ks = 0; ks < 2; ks++) {
                bfrag pf[2];
                #pragma unroll
                for (int i = 0; i < 2; i++)
                    pf[i] = *(const bfrag*)
                        ((const char*)&QP[w][16 * i + col][0] +
                         16 * ((4 * ks + quad) ^ (col & 7)));
                #pragma unroll
                for (int d4 = 0; d4 < 4; d4++)
                    #pragma unroll
                    for (int i = 0; i < 2; i++)
                        o_[d4][i] = __builtin_amdgcn_mfma_f32_16x16x32_bf16(
                            (ks ? vB : vA)[d4], pf[i], o_[d4][i], 0, 0, 0);
                #pragma unroll
                for (int i = 0; i < 2; i++)
                    ol[i] = __builtin_amdgcn_mfma_f32_16x16x32_bf16(
                        ones, pf[i], ol[i], 0, 0, 0);
            }
        }

        __syncthreads();   // compute done; next K tile's loads drained here
    }

    // ---- epilogue ----
    if (nc == 1) {
        // direct normalized write
        #pragma unroll
        for (int i = 0; i < 2; i++) {
            const float inv = 1.0f / ol[i][0];
            const int qg = q0 + 32 * w + 16 * i + col;
            #pragma unroll
            for (int d4 = 0; d4 < 4; d4++) {
                us4 pk;
                #pragma unroll
                for (int r2 = 0; r2 < 4; r2++) pk[r2] = f2bf(o_[d4][i][r2] * inv);
                *(us4*)&ctxb[(size_t)qg * EMB + h * HD + 16 * d4 + 4 * quad] = pk;
            }
        }
    } else {
        // partial write: bf16 O + fp32 l
        const int jj = (qi <= 21) ? (qi - 11) * 2 + ch : 22 + (qi - 22) * 3 + ch;
        const int slot = h * SLOTS_PER_HEAD + jj;
        u16* po = pO + (size_t)slot * (128 * 64);
        float* pl = pL + slot * 128;
        #pragma unroll
        for (int i = 0; i < 2; i++) {
            const int qrow = 32 * w + 16 * i + col;
            #pragma unroll
            for (int d4 = 0; d4 < 4; d4++) {
                us4 pk;
                #pragma unroll
                for (int r2 = 0; r2 < 4; r2++) pk[r2] = f2bf(o_[d4][i][r2]);
                *(us4*)&po[(size_t)qrow * 64 + 16 * d4 + 4 * quad] = pk;
            }
            if (quad == 0) pl[qrow] = ol[i][0];
        }
    }
}

// ---------------------------------------------------------------------------
// combine: out[q] = (sum_p O_p[q]) / (sum_p l_p[q]) over a group's 2-3 chunks.
// grid = 16 heads x 21 split q-blocks (qi 11..31) = 336.
// ---------------------------------------------------------------------------
__global__ __launch_bounds__(256)
void combine_kernel(const u16* __restrict__ pO, const float* __restrict__ pL,
                    u16* __restrict__ ctxb) {
    const int g = blockIdx.x;                  // 0..335
    const int h = g / 21, qq = g % 21;
    const int qi = 11 + qq;
    const int nc = (qi <= 21) ? 2 : 3;
    const int jj0 = (qi <= 21) ? (qi - 11) * 2 : 22 + (qi - 22) * 3;
    const int slot0 = h * SLOTS_PER_HEAD + jj0;

    const int t = threadIdx.x;
    const int q = t >> 1, dh = (t & 1) * 32;

    float l = 0.f;
    for (int p = 0; p < nc; p++) l += pL[(slot0 + p) * 128 + q];
    const float inv = 1.0f / l;

    u16* op = ctxb + (size_t)(qi * 128 + q) * EMB + h * HD + dh;

    #pragma unroll
    for (int j = 0; j < 4; j++) {
        float s[8] = {0.f, 0.f, 0.f, 0.f, 0.f, 0.f, 0.f, 0.f};
        for (int p = 0; p < nc; p++) {
            const us8 va = *(const us8*)
                (pO + ((size_t)(slot0 + p) * 128 + q) * 64 + dh + 8 * j);
            #pragma unroll
            for (int e = 0; e < 8; e++) s[e] += bf2f(va[e]);
        }
        us8 vo;
        #pragma unroll
        for (int e = 0; e < 8; e++) vo[e] = f2bf(s[e] * inv);
        *(us8*)(op + 8 * j) = vo;
    }
}

// ---------------------------------------------------------------------------
extern "C" void kernel_launch(void* const* d_in, const int* in_sizes, int n_in,
                              void* d_out, int out_size, void* d_ws, size_t ws_size,
                              hipStream_t stream) {
    const float* x      = (const float*)d_in[0];
    const float* wqkv_w = (const float*)d_in[2];
    const float* wqkv_b = (const float*)d_in[3];
    const float* out_w  = (const float*)d_in[4];
    const float* out_b  = (const float*)d_in[5];
    float* out = (float*)d_out;

    u16* qkvb = (u16*)d_ws;                        // [4096][3072] (V unused)
    u16* ctxb = qkvb + (size_t)S_LEN * E3;         // [4096][1024]
    u16* xb   = ctxb + (size_t)S_LEN * EMB;        // [4096][1024]
    u16* wt   = xb   + (size_t)S_LEN * EMB;        // [3072][1024]
    u16* owt  = wt   + (size_t)E3 * EMB;           // [1024][1024]
    u16* vtb  = owt  + (size_t)EMB * EMB;          // [16][64][4096]

    // flash partials alias the dead contiguous xb+wt span (14.68 MB):
    //   pO: 832 slots x 128x64 bf16 = 13.63 MB, pL: 832x128 f32 = 0.43 MB
    u16*   pO = xb;
    float* pL = (float*)(xb + (size_t)NSLOTS * 128 * 64);

    // RoPE table (1 MB) aliases ctxb: dead until flash writes it, read only
    // by gemm1's epilogue.
    float2* ropetab = (float2*)ctxb;

    dim3 blk(256);

    rope_tab_kernel<<<dim3(S_LEN * 32 / 256), blk, 0, stream>>>(ropetab);
    cast_bf16_kernel<<<dim3(S_LEN * EMB / (256 * 8)), blk, 0, stream>>>(x, xb);
    transpose_cast_kernel<<<dim3(EMB / 64, E3 / 64), blk, 0, stream>>>(
        wqkv_w, wt, EMB, E3);
    transpose_cast_kernel<<<dim3(EMB / 64, EMB / 64), blk, 0, stream>>>(
        out_w, owt, EMB, EMB);

    // QKV projection + fused RoPE (+ q pre-scale) + fused V transpose
    gemm_bt_kernel<1, 4, 1, 3><<<dim3(S_LEN / 128, E3 / 128), blk, 0, stream>>>(
        xb, wt, wqkv_b, qkvb, vtb, ropetab, S_LEN, E3, EMB);

    flash11_kernel<<<dim3(1008), blk, 0, stream>>>(qkvb, vtb, ctxb, pO, pL);
    combine_kernel<<<dim3(336), blk, 0, stream>>>(pO, pL, ctxb);

    // output projection, 128x64 tiles -> 512 blocks (2/CU)
    gemm_bt_kernel<0, 2, 0, 2><<<dim3(S_LEN / 128, EMB / 64), blk, 0, stream>>>(
        ctxb, owt, out_b, out, nullptr, nullptr, S_LEN, EMB, EMB);
}

// Round 3
// 335.286 us; speedup vs baseline: 1.0288x; 1.0288x over previous
//
#include <hip/hip_runtime.h>
#include <hip/hip_bf16.h>
#include <math.h>

#define S_LEN 4096
#define EMB   1024
#define E3    3072
#define NH    16
#define HD    64

// flash partial-combine geometry: qi<=10 direct; qi 11..21 -> 2 chunks;
// qi 22..31 -> 3 chunks.  52 partial slots per head, 832 total.
#define SLOTS_PER_HEAD 52
#define NSLOTS         832

typedef unsigned short u16;
typedef short          bfrag __attribute__((ext_vector_type(8)));  // 8 bf16
typedef float          ffrag __attribute__((ext_vector_type(4)));  // 4 f32
typedef unsigned short us8   __attribute__((ext_vector_type(8)));
typedef unsigned short us4   __attribute__((ext_vector_type(4)));

__device__ __forceinline__ u16 f2bf(float f) {
    union { float f; unsigned u; } v; v.f = f;
    unsigned r = v.u + 0x7fffu + ((v.u >> 16) & 1u);
    return (u16)(r >> 16);
}
__device__ __forceinline__ float bf2f(u16 b) {
    union { unsigned u; float f; } v; v.u = ((unsigned)b) << 16;
    return v.f;
}
// pack two f32 -> two bf16 (truncation) in one v_perm_b32
__device__ __forceinline__ unsigned pack_bf16_trunc(float lo, float hi) {
    union { float f; unsigned u; } a, b; a.f = lo; b.f = hi;
    return __builtin_amdgcn_perm(b.u, a.u, 0x07060302u);
}
// async global->LDS, 16B per lane; LDS dest = uniform base + lane*16
__device__ __forceinline__ void gld16(const void* g, void* l) {
    __builtin_amdgcn_global_load_lds(
        (const __attribute__((address_space(1))) unsigned int*)g,
        (__attribute__((address_space(3))) unsigned int*)l, 16, 0, 0);
}

// ---------------------------------------------------------------------------
// RoPE cos/sin table: tab[s][j] = (cos, sin)(s * 10000^(-j/32)), j < 32.
// 1 MB; aliases ctxb (dead until flash writes it).  Same sincosf as the old
// gemm epilogue -> bit-identical values.
// ---------------------------------------------------------------------------
__global__ __launch_bounds__(256)
void rope_tab_kernel(float2* __restrict__ tab) {
    const int idx = blockIdx.x * 256 + threadIdx.x;   // s*32 + j
    const int s = idx >> 5, j = idx & 31;
    const float C = 13.287712379549449f / 32.0f;      // log2(10000)/32
    const float invf = exp2f(-(float)j * C);
    float sn, cs;
    sincosf((float)s * invf, &sn, &cs);
    tab[idx] = make_float2(cs, sn);
}

// ---------------------------------------------------------------------------
// cast fp32 -> bf16, 8 elems/thread
// ---------------------------------------------------------------------------
__global__ __launch_bounds__(256)
void cast_bf16_kernel(const float* __restrict__ in, u16* __restrict__ out) {
    const size_t i = ((size_t)blockIdx.x * 256 + threadIdx.x) * 8;
    float4 a = *(const float4*)(in + i);
    float4 b = *(const float4*)(in + i + 4);
    us8 o;
    o[0]=f2bf(a.x); o[1]=f2bf(a.y); o[2]=f2bf(a.z); o[3]=f2bf(a.w);
    o[4]=f2bf(b.x); o[5]=f2bf(b.y); o[6]=f2bf(b.z); o[7]=f2bf(b.w);
    *(us8*)(out + i) = o;
}

// ---------------------------------------------------------------------------
// transpose+cast: in [R][C] fp32 -> out [C][R] bf16.  64x64 tiles.
// ---------------------------------------------------------------------------
__global__ __launch_bounds__(256)
void transpose_cast_kernel(const float* __restrict__ in, u16* __restrict__ out,
                           int R, int C) {
    __shared__ u16 T[64][72];
    const int r0 = blockIdx.x * 64, c0 = blockIdx.y * 64;
    const int t = threadIdx.x;
    const int rr = t >> 2, cc = (t & 3) * 16;

    const float* ip = in + (size_t)(r0 + rr) * C + c0 + cc;
    u16 tmp[16];
    #pragma unroll
    for (int i4 = 0; i4 < 4; i4++) {
        float4 v = ((const float4*)ip)[i4];
        tmp[4*i4+0]=f2bf(v.x); tmp[4*i4+1]=f2bf(v.y);
        tmp[4*i4+2]=f2bf(v.z); tmp[4*i4+3]=f2bf(v.w);
    }
    #pragma unroll
    for (int i8 = 0; i8 < 2; i8++) {
        us8 vv;
        #pragma unroll
        for (int j = 0; j < 8; j++) vv[j] = tmp[8*i8+j];
        *(us8*)&T[rr][cc + 8*i8] = vv;
    }
    __syncthreads();

    const int oc = t >> 2, orr = (t & 3) * 16;
    u16 ot[16];
    #pragma unroll
    for (int j = 0; j < 16; j++) ot[j] = T[orr + j][oc];
    u16* op = out + (size_t)(c0 + oc) * R + r0 + orr;
    #pragma unroll
    for (int i8 = 0; i8 < 2; i8++) {
        us8 vv;
        #pragma unroll
        for (int j = 0; j < 8; j++) vv[j] = ot[8*i8+j];
        *(us8*)(op + 8*i8) = vv;
    }
}

// ---------------------------------------------------------------------------
// bf16 MFMA GEMM, double-buffered: C[M,N] = A[M,K] * Bt[N,K]^T + bias
// Tile 128 x (32*NT); 4 waves as 2m x 2n; wave does 4x NT 16x16x32 tiles.
// ROPE=1 (requires NT=4):
//   n0 <  2048 : fuse RoPE rotation (+0.125*log2e scale for q) -> Cv (qkvb)
//                cos/sin from precomputed table (rope)
//   n0 >= 2048 : V region -- write bias-added values TRANSPOSED to vtp[d][s]
// ---------------------------------------------------------------------------
template <int OUT_BF16, int NT, int ROPE, int MINW>
__global__ __launch_bounds__(256, MINW)
void gemm_bt_kernel(const u16* __restrict__ A, const u16* __restrict__ Bt,
                    const float* __restrict__ bias, void* __restrict__ Cv,
                    u16* __restrict__ vtp, const float2* __restrict__ rope,
                    int M, int N, int K) {
    constexpr int BN = 32 * NT;       // block n-span
    constexpr int WS = 16 * NT;       // wave n-span
    __shared__ u16 As[2][128][32];
    __shared__ u16 Bs[2][BN][32];

    const int tid = threadIdx.x;
    const int w = tid >> 6, L = tid & 63;
    const int col = L & 15, quad = L >> 4;
    const int wm = w & 1, wn = w >> 1;
    const int m0 = blockIdx.x * 128, n0 = blockIdx.y * BN;

    ffrag acc[4][NT];
    #pragma unroll
    for (int a = 0; a < 4; a++)
        #pragma unroll
        for (int b = 0; b < NT; b++)
            #pragma unroll
            for (int r = 0; r < 4; r++) acc[a][b][r] = 0.f;

    const int srow = L >> 2;
    const int schk = L & 3;

    // prologue: stage k=0 into buf 0
    #pragma unroll
    for (int t = 0; t < 2; t++) {
        const int rg = (2 * w + t) * 16;
        gld16(A + (size_t)(m0 + rg + srow) * K + schk * 8, &As[0][rg][0]);
    }
    #pragma unroll
    for (int t = 0; t < NT / 2; t++) {
        const int rg = (w * (NT / 2) + t) * 16;
        gld16(Bt + (size_t)(n0 + rg + srow) * K + schk * 8, &Bs[0][rg][0]);
    }
    __syncthreads();

    int buf = 0;
    for (int k0 = 0; k0 < K; k0 += 32, buf ^= 1) {
        if (k0 + 32 < K) {
            #pragma unroll
            for (int t = 0; t < 2; t++) {
                const int rg = (2 * w + t) * 16;
                gld16(A + (size_t)(m0 + rg + srow) * K + k0 + 32 + schk * 8,
                      &As[buf ^ 1][rg][0]);
            }
            #pragma unroll
            for (int t = 0; t < NT / 2; t++) {
                const int rg = (w * (NT / 2) + t) * 16;
                gld16(Bt + (size_t)(n0 + rg + srow) * K + k0 + 32 + schk * 8,
                      &Bs[buf ^ 1][rg][0]);
            }
        }

        bfrag af[4], bf[NT];
        #pragma unroll
        for (int mt = 0; mt < 4; mt++)
            af[mt] = *(const bfrag*)&As[buf][64 * wm + 16 * mt + col][8 * quad];
        #pragma unroll
        for (int nt = 0; nt < NT; nt++)
            bf[nt] = *(const bfrag*)&Bs[buf][WS * wn + 16 * nt + col][8 * quad];
        #pragma unroll
        for (int mt = 0; mt < 4; mt++)
            #pragma unroll
            for (int nt = 0; nt < NT; nt++)
                acc[mt][nt] = __builtin_amdgcn_mfma_f32_16x16x32_bf16(
                    af[mt], bf[nt], acc[mt][nt], 0, 0, 0);

        __syncthreads();
    }

    float bv[NT];
    #pragma unroll
    for (int nt = 0; nt < NT; nt++) bv[nt] = bias[n0 + WS * wn + 16 * nt + col];

    if (ROPE && n0 < 2 * EMB) {
        // q (n<1024) or k (1024..2047): rotate (d, d+32) pairs, table lookup.
        const float SCq = (n0 < EMB) ? 0.125f * 1.44269504088896f : 1.0f;
        #pragma unroll
        for (int mt = 0; mt < 4; mt++) {
            #pragma unroll
            for (int r = 0; r < 4; r++) {
                const int mrow = m0 + 64 * wm + 16 * mt + 4 * quad + r;
                u16* cp = (u16*)Cv + (size_t)mrow * N + n0 + 64 * wn + col;
                #pragma unroll
                for (int pr = 0; pr < 2; pr++) {
                    const float2 t = rope[(size_t)mrow * 32 + col + 16 * pr];
                    const float cs = t.x, sn = t.y;
                    const float t1 = acc[mt][pr][r] + bv[pr];
                    const float t2 = acc[mt][pr + 2][r] + bv[pr + 2];
                    cp[16 * pr]      = f2bf((t1 * cs - t2 * sn) * SCq);
                    cp[16 * pr + 32] = f2bf((t2 * cs + t1 * sn) * SCq);
                }
            }
        }
    } else if (ROPE) {
        // V region: write transposed to vtp[d][s], d = n - 2048.
        #pragma unroll
        for (int nt = 0; nt < NT; nt++) {
            const int dg = n0 - 2 * EMB + WS * wn + 16 * nt + col;
            #pragma unroll
            for (int mt = 0; mt < 4; mt++) {
                const int s0 = m0 + 64 * wm + 16 * mt + 4 * quad;
                us4 pk;
                #pragma unroll
                for (int r = 0; r < 4; r++) pk[r] = f2bf(acc[mt][nt][r] + bv[nt]);
                *(us4*)&vtp[(size_t)dg * S_LEN + s0] = pk;
            }
        }
    } else {
        #pragma unroll
        for (int mt = 0; mt < 4; mt++) {
            #pragma unroll
            for (int r = 0; r < 4; r++) {
                const int m = m0 + 64 * wm + 16 * mt + 4 * quad + r;
                #pragma unroll
                for (int nt = 0; nt < NT; nt++) {
                    const int n = n0 + WS * wn + 16 * nt + col;
                    const float val = acc[mt][nt][r] + bv[nt];
                    if (OUT_BF16) ((u16*)Cv)[(size_t)m * N + n] = f2bf(val);
                    else          ((float*)Cv)[(size_t)m * N + n] = val;
                }
            }
        }
    }
}

// ---------------------------------------------------------------------------
// flash12: flash10 inner loop (K AND V staged in LDS -- flash11's direct-L2 V
// quadruplicated reads, thrashed L2, 227 MB write amplification; reverted),
// but SINGLE-buffered K and V with a two-barrier loop:
//   QK^T(Ks) -> softmax -> BARRIER1 (drains V[t] issued last iter)
//   -> issue K[t+1] -> PV(Vs) -> BARRIER2 (drains K[t+1]) -> issue V[t+1]
// K-prefetch overlaps PV; V-prefetch overlaps QK^T+softmax.  Correctness
// rests on __syncthreads draining each wave's own global_load_lds (vmcnt(0))
// before barrier release.
// LDS: 16 KB QP + 8 KB Ks + 8 KB Vs = 32 KB -> 5 blocks/CU (160 KB exactly),
// 20 waves/CU; all 1008 blocks resident from t=0 (capacity 1280).
// Schedule (unchanged): qi<=10 direct; qi 11..21 2 chunks; qi 22..31 3.
// ---------------------------------------------------------------------------
__global__ __launch_bounds__(256, 5)
void flash12_kernel(const u16* __restrict__ qkvb, const u16* __restrict__ vt,
                    u16* __restrict__ ctxb, u16* __restrict__ pO,
                    float* __restrict__ pL) {
    __shared__ u16 QP[4][32][64];     // per-wave: Q rows, then P overlay
    __shared__ u16 Ks[64][64];
    __shared__ u16 Vs[64][64];

    const int id = blockIdx.x;                    // 0..1007
    const int x  = id & 7;                        // XCD
    const int tt = id >> 3;                       // 0..125
    const int h  = x + 8 * (tt & 1);              // 2 heads per XCD, interleaved
    const int o  = tt >> 1;                       // 0..62 order index, long-first

    int qi, ch, nc;
    if (o < 30)      { qi = 31 - o / 3;        ch = o % 3;        nc = 3; }
    else if (o < 33) { qi = 10 - (o - 30);     ch = 0;            nc = 1; }
    else if (o < 55) { const int oo = o - 33;  qi = 21 - oo / 2;  ch = oo & 1; nc = 2; }
    else             { qi = 7 - (o - 55);      ch = 0;            nc = 1; }

    const int total = 2 * qi + 2;
    const int Lc    = (total + nc - 1) / nc;
    const int kt0   = ch * Lc;
    const int cnt   = min(Lc, total - kt0);
    const bool lastch = (kt0 + cnt == total);     // chunk holding the diagonal
    const int q0 = qi * 128;

    const int tid = threadIdx.x;
    const int w = tid >> 6, L = tid & 63;
    const int col = L & 15, quad = L >> 4;
    const int lr = L >> 3, lp = L & 7;
    const int lc = lp ^ lr;                       // swizzled chunk for staging

    const bool domask = lastch;
    const int nwt = cnt - ((domask && w < 2) ? 1 : 0);

    const size_t kArow = (size_t)(16 * w + lr) * E3 + EMB + h * HD + lc * 8;
    const size_t vArow = ((size_t)h * HD + 16 * w + lr) * S_LEN + lc * 8;
    const size_t kt0off  = (size_t)kt0 * 64 * E3;
    const size_t vt0off  = (size_t)kt0 * 64;

    // ---- stage Q (own wave's 32 rows) + K/V tile kt0 ----
    #pragma unroll
    for (int u = 0; u < 4; u++)
        gld16(qkvb + (size_t)(q0 + 32 * w + 8 * u + lr) * E3 + h * HD + lc * 8,
              &QP[w][8 * u][0]);
    #pragma unroll
    for (int u = 0; u < 2; u++) {
        gld16(qkvb + kArow + kt0off + (size_t)(8 * u) * E3,
              &Ks[16 * w + 8 * u][0]);
        gld16(vt + vArow + vt0off + (size_t)(8 * u) * S_LEN,
              &Vs[16 * w + 8 * u][0]);
    }
    __syncthreads();

    bfrag qf[2][2];
    #pragma unroll
    for (int i = 0; i < 2; i++)
        #pragma unroll
        for (int ks = 0; ks < 2; ks++)
            qf[i][ks] = *(const bfrag*)
                ((const char*)&QP[w][16 * i + col][0] +
                 16 * ((4 * ks + quad) ^ (col & 7)));

    bfrag ones;
    #pragma unroll
    for (int i = 0; i < 8; i++) ones[i] = (short)0x3F80;

    ffrag o_[4][2], ol[2];
    #pragma unroll
    for (int d4 = 0; d4 < 4; d4++)
        #pragma unroll
        for (int i = 0; i < 2; i++)
            #pragma unroll
            for (int r2 = 0; r2 < 4; r2++) o_[d4][i][r2] = 0.f;
    #pragma unroll
    for (int i = 0; i < 2; i++)
        #pragma unroll
        for (int r2 = 0; r2 < 4; r2++) ol[i][r2] = 0.f;

    #pragma unroll 1
    for (int t = 0; t < cnt; t++) {
        if (t < nwt) {
            // ---- S^T = K Q^T ----
            ffrag st[4][2];
            #pragma unroll
            for (int t4 = 0; t4 < 4; t4++)
                #pragma unroll
                for (int i = 0; i < 2; i++)
                    #pragma unroll
                    for (int r2 = 0; r2 < 4; r2++) st[t4][i][r2] = 0.f;
            #pragma unroll
            for (int ks = 0; ks < 2; ks++) {
                bfrag kf[4];
                #pragma unroll
                for (int t4 = 0; t4 < 4; t4++)
                    kf[t4] = *(const bfrag*)
                        &Ks[16 * t4 + col][(((4 * ks + quad) ^ (col & 7)) * 8)];
                #pragma unroll
                for (int t4 = 0; t4 < 4; t4++)
                    #pragma unroll
                    for (int i = 0; i < 2; i++)
                        st[t4][i] = __builtin_amdgcn_mfma_f32_16x16x32_bf16(
                            kf[t4], qf[i][ks], st[t4][i], 0, 0, 0);
            }

            // ---- causal mask: only this wave's diagonal tile ----
            if (domask && t == nwt - 1) {
                #pragma unroll
                for (int i = 0; i < 2; i++) {
                    const int qrel = 32 * (w & 1) + 16 * i + col;
                    #pragma unroll
                    for (int t4 = 0; t4 < 4; t4++) {
                        const int key0 = 16 * t4 + 4 * quad;
                        #pragma unroll
                        for (int r2 = 0; r2 < 4; r2++)
                            if (key0 + r2 > qrel) st[t4][i][r2] = -3.0e38f;
                    }
                }
            }

            // ---- softmax numerator: p = exp2(s), no shift ----
            #pragma unroll
            for (int i = 0; i < 2; i++) {
                const int prow = 16 * i + col;
                #pragma unroll
                for (int t4 = 0; t4 < 4; t4++) {
                    float pr[4];
                    #pragma unroll
                    for (int r2 = 0; r2 < 4; r2++) pr[r2] = exp2f(st[t4][i][r2]);
                    uint2 pk;
                    pk.x = pack_bf16_trunc(pr[0], pr[1]);
                    pk.y = pack_bf16_trunc(pr[2], pr[3]);
                    const int c2 = (2 * t4 + (quad >> 1)) ^ (col & 7);
                    *(uint2*)((char*)&QP[w][prow][0] + 16 * c2 + 8 * (quad & 1)) = pk;
                }
            }
        }

        // BARRIER1: all waves done reading Ks[t]; each wave's V[t] staging
        // loads (issued at end of previous iteration) are drained here.
        __syncthreads();

        // issue K[t+1] into Ks (safe: QK^T of t complete for all waves)
        if (t + 1 < cnt) {
            const size_t ko = kArow + kt0off + (size_t)(t + 1) * 64 * E3;
            #pragma unroll
            for (int u = 0; u < 2; u++)
                gld16(qkvb + ko + (size_t)(8 * u) * E3, &Ks[16 * w + 8 * u][0]);
        }

        if (t < nwt) {
            // ---- O^T += V^T P^T ;  l += 1^T P^T ----
            #pragma unroll
            for (int ks = 0; ks < 2; ks++) {
                bfrag vf[4];
                #pragma unroll
                for (int d4 = 0; d4 < 4; d4++)
                    vf[d4] = *(const bfrag*)
                        &Vs[16 * d4 + col][(((4 * ks + quad) ^ (col & 7)) * 8)];
                bfrag pf[2];
                #pragma unroll
                for (int i = 0; i < 2; i++)
                    pf[i] = *(const bfrag*)
                        ((const char*)&QP[w][16 * i + col][0] +
                         16 * ((4 * ks + quad) ^ (col & 7)));
                #pragma unroll
                for (int d4 = 0; d4 < 4; d4++)
                    #pragma unroll
                    for (int i = 0; i < 2; i++)
                        o_[d4][i] = __builtin_amdgcn_mfma_f32_16x16x32_bf16(
                            vf[d4], pf[i], o_[d4][i], 0, 0, 0);
                #pragma unroll
                for (int i = 0; i < 2; i++)
                    ol[i] = __builtin_amdgcn_mfma_f32_16x16x32_bf16(
                        ones, pf[i], ol[i], 0, 0, 0);
            }
        }

        // BARRIER2: all waves done reading Vs[t]; K[t+1] staging drained.
        __syncthreads();

        // issue V[t+1] into Vs (safe: PV of t complete for all waves)
        if (t + 1 < cnt) {
            const size_t vo = vArow + vt0off + (size_t)(t + 1) * 64;
            #pragma unroll
            for (int u = 0; u < 2; u++)
                gld16(vt + vo + (size_t)(8 * u) * S_LEN, &Vs[16 * w + 8 * u][0]);
        }
    }

    // ---- epilogue ----
    if (nc == 1) {
        // direct normalized write
        #pragma unroll
        for (int i = 0; i < 2; i++) {
            const float inv = 1.0f / ol[i][0];
            const int qg = q0 + 32 * w + 16 * i + col;
            #pragma unroll
            for (int d4 = 0; d4 < 4; d4++) {
                us4 pk;
                #pragma unroll
                for (int r2 = 0; r2 < 4; r2++) pk[r2] = f2bf(o_[d4][i][r2] * inv);
                *(us4*)&ctxb[(size_t)qg * EMB + h * HD + 16 * d4 + 4 * quad] = pk;
            }
        }
    } else {
        // partial write: bf16 O + fp32 l
        const int jj = (qi <= 21) ? (qi - 11) * 2 + ch : 22 + (qi - 22) * 3 + ch;
        const int slot = h * SLOTS_PER_HEAD + jj;
        u16* po = pO + (size_t)slot * (128 * 64);
        float* pl = pL + slot * 128;
        #pragma unroll
        for (int i = 0; i < 2; i++) {
            const int qrow = 32 * w + 16 * i + col;
            #pragma unroll
            for (int d4 = 0; d4 < 4; d4++) {
                us4 pk;
                #pragma unroll
                for (int r2 = 0; r2 < 4; r2++) pk[r2] = f2bf(o_[d4][i][r2]);
                *(us4*)&po[(size_t)qrow * 64 + 16 * d4 + 4 * quad] = pk;
            }
            if (quad == 0) pl[qrow] = ol[i][0];
        }
    }
}

// ---------------------------------------------------------------------------
// combine: out[q] = (sum_p O_p[q]) / (sum_p l_p[q]) over a group's 2-3 chunks.
// grid = 16 heads x 21 split q-blocks (qi 11..31) = 336.
// ---------------------------------------------------------------------------
__global__ __launch_bounds__(256)
void combine_kernel(const u16* __restrict__ pO, const float* __restrict__ pL,
                    u16* __restrict__ ctxb) {
    const int g = blockIdx.x;                  // 0..335
    const int h = g / 21, qq = g % 21;
    const int qi = 11 + qq;
    const int nc = (qi <= 21) ? 2 : 3;
    const int jj0 = (qi <= 21) ? (qi - 11) * 2 : 22 + (qi - 22) * 3;
    const int slot0 = h * SLOTS_PER_HEAD + jj0;

    const int t = threadIdx.x;
    const int q = t >> 1, dh = (t & 1) * 32;

    float l = 0.f;
    for (int p = 0; p < nc; p++) l += pL[(slot0 + p) * 128 + q];
    const float inv = 1.0f / l;

    u16* op = ctxb + (size_t)(qi * 128 + q) * EMB + h * HD + dh;

    #pragma unroll
    for (int j = 0; j < 4; j++) {
        float s[8] = {0.f, 0.f, 0.f, 0.f, 0.f, 0.f, 0.f, 0.f};
        for (int p = 0; p < nc; p++) {
            const us8 va = *(const us8*)
                (pO + ((size_t)(slot0 + p) * 128 + q) * 64 + dh + 8 * j);
            #pragma unroll
            for (int e = 0; e < 8; e++) s[e] += bf2f(va[e]);
        }
        us8 vo;
        #pragma unroll
        for (int e = 0; e < 8; e++) vo[e] = f2bf(s[e] * inv);
        *(us8*)(op + 8 * j) = vo;
    }
}

// ---------------------------------------------------------------------------
extern "C" void kernel_launch(void* const* d_in, const int* in_sizes, int n_in,
                              void* d_out, int out_size, void* d_ws, size_t ws_size,
                              hipStream_t stream) {
    const float* x      = (const float*)d_in[0];
    const float* wqkv_w = (const float*)d_in[2];
    const float* wqkv_b = (const float*)d_in[3];
    const float* out_w  = (const float*)d_in[4];
    const float* out_b  = (const float*)d_in[5];
    float* out = (float*)d_out;

    u16* qkvb = (u16*)d_ws;                        // [4096][3072] (V unused)
    u16* ctxb = qkvb + (size_t)S_LEN * E3;         // [4096][1024]
    u16* xb   = ctxb + (size_t)S_LEN * EMB;        // [4096][1024]
    u16* wt   = xb   + (size_t)S_LEN * EMB;        // [3072][1024]
    u16* owt  = wt   + (size_t)E3 * EMB;           // [1024][1024]
    u16* vtb  = owt  + (size_t)EMB * EMB;          // [16][64][4096]

    // flash partials alias the dead contiguous xb+wt span (14.68 MB):
    //   pO: 832 slots x 128x64 bf16 = 13.63 MB, pL: 832x128 f32 = 0.43 MB
    u16*   pO = xb;
    float* pL = (float*)(xb + (size_t)NSLOTS * 128 * 64);

    // RoPE table (1 MB) aliases ctxb: dead until flash writes it, read only
    // by gemm1's epilogue.
    float2* ropetab = (float2*)ctxb;

    dim3 blk(256);

    rope_tab_kernel<<<dim3(S_LEN * 32 / 256), blk, 0, stream>>>(ropetab);
    cast_bf16_kernel<<<dim3(S_LEN * EMB / (256 * 8)), blk, 0, stream>>>(x, xb);
    transpose_cast_kernel<<<dim3(EMB / 64, E3 / 64), blk, 0, stream>>>(
        wqkv_w, wt, EMB, E3);
    transpose_cast_kernel<<<dim3(EMB / 64, EMB / 64), blk, 0, stream>>>(
        out_w, owt, EMB, EMB);

    // QKV projection + fused RoPE (+ q pre-scale) + fused V transpose
    gemm_bt_kernel<1, 4, 1, 3><<<dim3(S_LEN / 128, E3 / 128), blk, 0, stream>>>(
        xb, wt, wqkv_b, qkvb, vtb, ropetab, S_LEN, E3, EMB);

    flash12_kernel<<<dim3(1008), blk, 0, stream>>>(qkvb, vtb, ctxb, pO, pL);
    combine_kernel<<<dim3(336), blk, 0, stream>>>(pO, pL, ctxb);

    // output projection, 128x64 tiles -> 512 blocks (2/CU)
    gemm_bt_kernel<0, 2, 0, 2><<<dim3(S_LEN / 128, EMB / 64), blk, 0, stream>>>(
        ctxb, owt, out_b, out, nullptr, nullptr, S_LEN, EMB, EMB);
}

// Round 4
// 246.442 us; speedup vs baseline: 1.3997x; 1.3605x over previous
//
#include <hip/hip_runtime.h>
#include <hip/hip_bf16.h>
#include <math.h>

#define S_LEN 4096
#define EMB   1024
#define E3    3072
#define NH    16
#define HD    64

// flash partial-combine geometry: qi<=10 direct; qi 11..21 -> 2 chunks;
// qi 22..31 -> 3 chunks.  52 partial slots per head, 832 total.
#define SLOTS_PER_HEAD 52
#define NSLOTS         832

typedef unsigned short u16;
typedef short          bfrag __attribute__((ext_vector_type(8)));  // 8 bf16
typedef float          ffrag __attribute__((ext_vector_type(4)));  // 4 f32
typedef unsigned short us8   __attribute__((ext_vector_type(8)));
typedef unsigned short us4   __attribute__((ext_vector_type(4)));

__device__ __forceinline__ u16 f2bf(float f) {
    union { float f; unsigned u; } v; v.f = f;
    unsigned r = v.u + 0x7fffu + ((v.u >> 16) & 1u);
    return (u16)(r >> 16);
}
__device__ __forceinline__ float bf2f(u16 b) {
    union { unsigned u; float f; } v; v.u = ((unsigned)b) << 16;
    return v.f;
}
// pack two f32 -> two bf16 (truncation) in one v_perm_b32
__device__ __forceinline__ unsigned pack_bf16_trunc(float lo, float hi) {
    union { float f; unsigned u; } a, b; a.f = lo; b.f = hi;
    return __builtin_amdgcn_perm(b.u, a.u, 0x07060302u);
}
// async global->LDS, 16B per lane; LDS dest = uniform base + lane*16
__device__ __forceinline__ void gld16(const void* g, void* l) {
    __builtin_amdgcn_global_load_lds(
        (const __attribute__((address_space(1))) unsigned int*)g,
        (__attribute__((address_space(3))) unsigned int*)l, 16, 0, 0);
}

// ---------------------------------------------------------------------------
// RoPE cos/sin table: tab[s][j] = (cos, sin)(s * 10000^(-j/32)), j < 32.
// 1 MB; aliases ctxb (dead until flash writes it).  Same sincosf as the old
// gemm epilogue -> bit-identical values.
// ---------------------------------------------------------------------------
__global__ __launch_bounds__(256)
void rope_tab_kernel(float2* __restrict__ tab) {
    const int idx = blockIdx.x * 256 + threadIdx.x;   // s*32 + j
    const int s = idx >> 5, j = idx & 31;
    const float C = 13.287712379549449f / 32.0f;      // log2(10000)/32
    const float invf = exp2f(-(float)j * C);
    float sn, cs;
    sincosf((float)s * invf, &sn, &cs);
    tab[idx] = make_float2(cs, sn);
}

// ---------------------------------------------------------------------------
// cast fp32 -> bf16, 8 elems/thread
// ---------------------------------------------------------------------------
__global__ __launch_bounds__(256)
void cast_bf16_kernel(const float* __restrict__ in, u16* __restrict__ out) {
    const size_t i = ((size_t)blockIdx.x * 256 + threadIdx.x) * 8;
    float4 a = *(const float4*)(in + i);
    float4 b = *(const float4*)(in + i + 4);
    us8 o;
    o[0]=f2bf(a.x); o[1]=f2bf(a.y); o[2]=f2bf(a.z); o[3]=f2bf(a.w);
    o[4]=f2bf(b.x); o[5]=f2bf(b.y); o[6]=f2bf(b.z); o[7]=f2bf(b.w);
    *(us8*)(out + i) = o;
}

// ---------------------------------------------------------------------------
// transpose+cast: in [R][C] fp32 -> out [C][R] bf16.  64x64 tiles.
// ---------------------------------------------------------------------------
__global__ __launch_bounds__(256)
void transpose_cast_kernel(const float* __restrict__ in, u16* __restrict__ out,
                           int R, int C) {
    __shared__ u16 T[64][72];
    const int r0 = blockIdx.x * 64, c0 = blockIdx.y * 64;
    const int t = threadIdx.x;
    const int rr = t >> 2, cc = (t & 3) * 16;

    const float* ip = in + (size_t)(r0 + rr) * C + c0 + cc;
    u16 tmp[16];
    #pragma unroll
    for (int i4 = 0; i4 < 4; i4++) {
        float4 v = ((const float4*)ip)[i4];
        tmp[4*i4+0]=f2bf(v.x); tmp[4*i4+1]=f2bf(v.y);
        tmp[4*i4+2]=f2bf(v.z); tmp[4*i4+3]=f2bf(v.w);
    }
    #pragma unroll
    for (int i8 = 0; i8 < 2; i8++) {
        us8 vv;
        #pragma unroll
        for (int j = 0; j < 8; j++) vv[j] = tmp[8*i8+j];
        *(us8*)&T[rr][cc + 8*i8] = vv;
    }
    __syncthreads();

    const int oc = t >> 2, orr = (t & 3) * 16;
    u16 ot[16];
    #pragma unroll
    for (int j = 0; j < 16; j++) ot[j] = T[orr + j][oc];
    u16* op = out + (size_t)(c0 + oc) * R + r0 + orr;
    #pragma unroll
    for (int i8 = 0; i8 < 2; i8++) {
        us8 vv;
        #pragma unroll
        for (int j = 0; j < 8; j++) vv[j] = ot[8*i8+j];
        *(us8*)(op + 8*i8) = vv;
    }
}

// ---------------------------------------------------------------------------
// bf16 MFMA GEMM, double-buffered: C[M,N] = A[M,K] * Bt[N,K]^T + bias
// Tile 128 x (32*NT); 4 waves as 2m x 2n; wave does 4x NT 16x16x32 tiles.
// ROPE=1 (requires NT=4):
//   n0 <  2048 : fuse RoPE rotation (+0.125*log2e scale for q) -> Cv (qkvb)
//                cos/sin from precomputed table (rope)
//   n0 >= 2048 : V region -- write bias-added values TRANSPOSED to vtp[d][s]
// ---------------------------------------------------------------------------
template <int OUT_BF16, int NT, int ROPE, int MINW>
__global__ __launch_bounds__(256, MINW)
void gemm_bt_kernel(const u16* __restrict__ A, const u16* __restrict__ Bt,
                    const float* __restrict__ bias, void* __restrict__ Cv,
                    u16* __restrict__ vtp, const float2* __restrict__ rope,
                    int M, int N, int K) {
    constexpr int BN = 32 * NT;       // block n-span
    constexpr int WS = 16 * NT;       // wave n-span
    __shared__ u16 As[2][128][32];
    __shared__ u16 Bs[2][BN][32];

    const int tid = threadIdx.x;
    const int w = tid >> 6, L = tid & 63;
    const int col = L & 15, quad = L >> 4;
    const int wm = w & 1, wn = w >> 1;
    const int m0 = blockIdx.x * 128, n0 = blockIdx.y * BN;

    ffrag acc[4][NT];
    #pragma unroll
    for (int a = 0; a < 4; a++)
        #pragma unroll
        for (int b = 0; b < NT; b++)
            #pragma unroll
            for (int r = 0; r < 4; r++) acc[a][b][r] = 0.f;

    const int srow = L >> 2;
    const int schk = L & 3;

    // prologue: stage k=0 into buf 0
    #pragma unroll
    for (int t = 0; t < 2; t++) {
        const int rg = (2 * w + t) * 16;
        gld16(A + (size_t)(m0 + rg + srow) * K + schk * 8, &As[0][rg][0]);
    }
    #pragma unroll
    for (int t = 0; t < NT / 2; t++) {
        const int rg = (w * (NT / 2) + t) * 16;
        gld16(Bt + (size_t)(n0 + rg + srow) * K + schk * 8, &Bs[0][rg][0]);
    }
    __syncthreads();

    int buf = 0;
    for (int k0 = 0; k0 < K; k0 += 32, buf ^= 1) {
        if (k0 + 32 < K) {
            #pragma unroll
            for (int t = 0; t < 2; t++) {
                const int rg = (2 * w + t) * 16;
                gld16(A + (size_t)(m0 + rg + srow) * K + k0 + 32 + schk * 8,
                      &As[buf ^ 1][rg][0]);
            }
            #pragma unroll
            for (int t = 0; t < NT / 2; t++) {
                const int rg = (w * (NT / 2) + t) * 16;
                gld16(Bt + (size_t)(n0 + rg + srow) * K + k0 + 32 + schk * 8,
                      &Bs[buf ^ 1][rg][0]);
            }
        }

        bfrag af[4], bf[NT];
        #pragma unroll
        for (int mt = 0; mt < 4; mt++)
            af[mt] = *(const bfrag*)&As[buf][64 * wm + 16 * mt + col][8 * quad];
        #pragma unroll
        for (int nt = 0; nt < NT; nt++)
            bf[nt] = *(const bfrag*)&Bs[buf][WS * wn + 16 * nt + col][8 * quad];
        #pragma unroll
        for (int mt = 0; mt < 4; mt++)
            #pragma unroll
            for (int nt = 0; nt < NT; nt++)
                acc[mt][nt] = __builtin_amdgcn_mfma_f32_16x16x32_bf16(
                    af[mt], bf[nt], acc[mt][nt], 0, 0, 0);

        __syncthreads();
    }

    float bv[NT];
    #pragma unroll
    for (int nt = 0; nt < NT; nt++) bv[nt] = bias[n0 + WS * wn + 16 * nt + col];

    if (ROPE && n0 < 2 * EMB) {
        // q (n<1024) or k (1024..2047): rotate (d, d+32) pairs, table lookup.
        const float SCq = (n0 < EMB) ? 0.125f * 1.44269504088896f : 1.0f;
        #pragma unroll
        for (int mt = 0; mt < 4; mt++) {
            #pragma unroll
            for (int r = 0; r < 4; r++) {
                const int mrow = m0 + 64 * wm + 16 * mt + 4 * quad + r;
                u16* cp = (u16*)Cv + (size_t)mrow * N + n0 + 64 * wn + col;
                #pragma unroll
                for (int pr = 0; pr < 2; pr++) {
                    const float2 t = rope[(size_t)mrow * 32 + col + 16 * pr];
                    const float cs = t.x, sn = t.y;
                    const float t1 = acc[mt][pr][r] + bv[pr];
                    const float t2 = acc[mt][pr + 2][r] + bv[pr + 2];
                    cp[16 * pr]      = f2bf((t1 * cs - t2 * sn) * SCq);
                    cp[16 * pr + 32] = f2bf((t2 * cs + t1 * sn) * SCq);
                }
            }
        }
    } else if (ROPE) {
        // V region: write transposed to vtp[d][s], d = n - 2048.
        #pragma unroll
        for (int nt = 0; nt < NT; nt++) {
            const int dg = n0 - 2 * EMB + WS * wn + 16 * nt + col;
            #pragma unroll
            for (int mt = 0; mt < 4; mt++) {
                const int s0 = m0 + 64 * wm + 16 * mt + 4 * quad;
                us4 pk;
                #pragma unroll
                for (int r = 0; r < 4; r++) pk[r] = f2bf(acc[mt][nt][r] + bv[nt]);
                *(us4*)&vtp[(size_t)dg * S_LEN + s0] = pk;
            }
        }
    } else {
        #pragma unroll
        for (int mt = 0; mt < 4; mt++) {
            #pragma unroll
            for (int r = 0; r < 4; r++) {
                const int m = m0 + 64 * wm + 16 * mt + 4 * quad + r;
                #pragma unroll
                for (int nt = 0; nt < NT; nt++) {
                    const int n = n0 + WS * wn + 16 * nt + col;
                    const float val = acc[mt][nt][r] + bv[nt];
                    if (OUT_BF16) ((u16*)Cv)[(size_t)m * N + n] = f2bf(val);
                    else          ((float*)Cv)[(size_t)m * N + n] = val;
                }
            }
        }
    }
}

// ---------------------------------------------------------------------------
// flash13: exact flash10 structure (K/V double-buffered LDS, 48 KB,
// launch_bounds(256,3) -- VGPR 68, zero scratch).  Rounds 2/3 proved the
// live register set (~170 incl. AGPRs, unified file, 512-reg/SIMD pool)
// spills to scratch at >=4 waves/SIMD: VGPR 68->64->48, HBM traffic
// 25->330->410 MB.  3 waves/SIMD is this loop's occupancy ceiling.
// Added vs flash10: s_setprio(1) around the MFMA clusters (T5: +4-7% attn
// when co-resident blocks sit at different phases; here 3 blocks/CU with
// independent tile indices).
// Schedule: qi<=10 direct; qi 11..21 2 chunks; qi 22..31 3 chunks;
// 1008 blocks, longest-first per XCD lane, id&7 = XCD, 2 heads/XCD.
// ---------------------------------------------------------------------------
__global__ __launch_bounds__(256, 3)
void flash13_kernel(const u16* __restrict__ qkvb, const u16* __restrict__ vt,
                    u16* __restrict__ ctxb, u16* __restrict__ pO,
                    float* __restrict__ pL) {
    __shared__ u16 QP[4][32][64];     // per-wave: Q rows, then P overlay
    __shared__ u16 Ks[2][64][64];
    __shared__ u16 Vs[2][64][64];

    const int id = blockIdx.x;                    // 0..1007
    const int x  = id & 7;                        // XCD
    const int tt = id >> 3;                       // 0..125
    const int h  = x + 8 * (tt & 1);              // 2 heads per XCD, interleaved
    const int o  = tt >> 1;                       // 0..62 order index, long-first

    int qi, ch, nc;
    if (o < 30)      { qi = 31 - o / 3;        ch = o % 3;        nc = 3; }
    else if (o < 33) { qi = 10 - (o - 30);     ch = 0;            nc = 1; }
    else if (o < 55) { const int oo = o - 33;  qi = 21 - oo / 2;  ch = oo & 1; nc = 2; }
    else             { qi = 7 - (o - 55);      ch = 0;            nc = 1; }

    const int total = 2 * qi + 2;
    const int Lc    = (total + nc - 1) / nc;
    const int kt0   = ch * Lc;
    const int cnt   = min(Lc, total - kt0);
    const bool lastch = (kt0 + cnt == total);     // chunk holding the diagonal
    const int q0 = qi * 128;

    const int tid = threadIdx.x;
    const int w = tid >> 6, L = tid & 63;
    const int col = L & 15, quad = L >> 4;
    const int lr = L >> 3, lp = L & 7;
    const int lc = lp ^ lr;                       // swizzled chunk for staging

    const bool domask = lastch;
    const int nwt = cnt - ((domask && w < 2) ? 1 : 0);

    const size_t kArow = (size_t)(16 * w + lr) * E3 + EMB + h * HD + lc * 8;
    const size_t vArow = ((size_t)h * HD + 16 * w + lr) * S_LEN + lc * 8;
    const size_t kt0off  = (size_t)kt0 * 64 * E3;
    const size_t vt0off  = (size_t)kt0 * 64;

    // ---- stage Q (own wave's 32 rows) + K/V tile kt0 ----
    #pragma unroll
    for (int u = 0; u < 4; u++)
        gld16(qkvb + (size_t)(q0 + 32 * w + 8 * u + lr) * E3 + h * HD + lc * 8,
              &QP[w][8 * u][0]);
    #pragma unroll
    for (int u = 0; u < 2; u++) {
        gld16(qkvb + kArow + kt0off + (size_t)(8 * u) * E3,
              &Ks[0][16 * w + 8 * u][0]);
        gld16(vt + vArow + vt0off + (size_t)(8 * u) * S_LEN,
              &Vs[0][16 * w + 8 * u][0]);
    }
    __syncthreads();

    bfrag qf[2][2];
    #pragma unroll
    for (int i = 0; i < 2; i++)
        #pragma unroll
        for (int ks = 0; ks < 2; ks++)
            qf[i][ks] = *(const bfrag*)
                ((const char*)&QP[w][16 * i + col][0] +
                 16 * ((4 * ks + quad) ^ (col & 7)));

    bfrag ones;
    #pragma unroll
    for (int i = 0; i < 8; i++) ones[i] = (short)0x3F80;

    ffrag o_[4][2], ol[2];
    #pragma unroll
    for (int d4 = 0; d4 < 4; d4++)
        #pragma unroll
        for (int i = 0; i < 2; i++)
            #pragma unroll
            for (int r2 = 0; r2 < 4; r2++) o_[d4][i][r2] = 0.f;
    #pragma unroll
    for (int i = 0; i < 2; i++)
        #pragma unroll
        for (int r2 = 0; r2 < 4; r2++) ol[i][r2] = 0.f;

    #pragma unroll 1
    for (int t = 0; t < cnt; t++) {
        const int buf = t & 1;
        // prefetch next k-tile into the other buffer (before compute)
        if (t + 1 < cnt) {
            const size_t ko = kArow + kt0off + (size_t)(t + 1) * 64 * E3;
            const size_t vo = vArow + vt0off + (size_t)(t + 1) * 64;
            #pragma unroll
            for (int u = 0; u < 2; u++) {
                gld16(qkvb + ko + (size_t)(8 * u) * E3,
                      &Ks[buf ^ 1][16 * w + 8 * u][0]);
                gld16(vt + vo + (size_t)(8 * u) * S_LEN,
                      &Vs[buf ^ 1][16 * w + 8 * u][0]);
            }
        }

        if (t < nwt) {
            // ---- S^T = K Q^T ----
            ffrag st[4][2];
            #pragma unroll
            for (int t4 = 0; t4 < 4; t4++)
                #pragma unroll
                for (int i = 0; i < 2; i++)
                    #pragma unroll
                    for (int r2 = 0; r2 < 4; r2++) st[t4][i][r2] = 0.f;
            __builtin_amdgcn_s_setprio(1);
            #pragma unroll
            for (int ks = 0; ks < 2; ks++) {
                bfrag kf[4];
                #pragma unroll
                for (int t4 = 0; t4 < 4; t4++)
                    kf[t4] = *(const bfrag*)
                        &Ks[buf][16 * t4 + col][(((4 * ks + quad) ^ (col & 7)) * 8)];
                #pragma unroll
                for (int t4 = 0; t4 < 4; t4++)
                    #pragma unroll
                    for (int i = 0; i < 2; i++)
                        st[t4][i] = __builtin_amdgcn_mfma_f32_16x16x32_bf16(
                            kf[t4], qf[i][ks], st[t4][i], 0, 0, 0);
            }
            __builtin_amdgcn_s_setprio(0);

            // ---- causal mask: only this wave's diagonal tile ----
            if (domask && t == nwt - 1) {
                #pragma unroll
                for (int i = 0; i < 2; i++) {
                    const int qrel = 32 * (w & 1) + 16 * i + col;
                    #pragma unroll
                    for (int t4 = 0; t4 < 4; t4++) {
                        const int key0 = 16 * t4 + 4 * quad;
                        #pragma unroll
                        for (int r2 = 0; r2 < 4; r2++)
                            if (key0 + r2 > qrel) st[t4][i][r2] = -3.0e38f;
                    }
                }
            }

            // ---- softmax numerator: p = exp2(s), no shift ----
            #pragma unroll
            for (int i = 0; i < 2; i++) {
                const int prow = 16 * i + col;
                #pragma unroll
                for (int t4 = 0; t4 < 4; t4++) {
                    float pr[4];
                    #pragma unroll
                    for (int r2 = 0; r2 < 4; r2++) pr[r2] = exp2f(st[t4][i][r2]);
                    uint2 pk;
                    pk.x = pack_bf16_trunc(pr[0], pr[1]);
                    pk.y = pack_bf16_trunc(pr[2], pr[3]);
                    const int c2 = (2 * t4 + (quad >> 1)) ^ (col & 7);
                    *(uint2*)((char*)&QP[w][prow][0] + 16 * c2 + 8 * (quad & 1)) = pk;
                }
            }

            // ---- O^T += V^T P^T ;  l += 1^T P^T ----
            __builtin_amdgcn_s_setprio(1);
            #pragma unroll
            for (int ks = 0; ks < 2; ks++) {
                bfrag vf[4];
                #pragma unroll
                for (int d4 = 0; d4 < 4; d4++)
                    vf[d4] = *(const bfrag*)
                        &Vs[buf][16 * d4 + col][(((4 * ks + quad) ^ (col & 7)) * 8)];
                bfrag pf[2];
                #pragma unroll
                for (int i = 0; i < 2; i++)
                    pf[i] = *(const bfrag*)
                        ((const char*)&QP[w][16 * i + col][0] +
                         16 * ((4 * ks + quad) ^ (col & 7)));
                #pragma unroll
                for (int d4 = 0; d4 < 4; d4++)
                    #pragma unroll
                    for (int i = 0; i < 2; i++)
                        o_[d4][i] = __builtin_amdgcn_mfma_f32_16x16x32_bf16(
                            vf[d4], pf[i], o_[d4][i], 0, 0, 0);
                #pragma unroll
                for (int i = 0; i < 2; i++)
                    ol[i] = __builtin_amdgcn_mfma_f32_16x16x32_bf16(
                        ones, pf[i], ol[i], 0, 0, 0);
            }
            __builtin_amdgcn_s_setprio(0);
        }

        __syncthreads();   // compute done; next tile's loads drained here
    }

    // ---- epilogue ----
    if (nc == 1) {
        // direct normalized write
        #pragma unroll
        for (int i = 0; i < 2; i++) {
            const float inv = 1.0f / ol[i][0];
            const int qg = q0 + 32 * w + 16 * i + col;
            #pragma unroll
            for (int d4 = 0; d4 < 4; d4++) {
                us4 pk;
                #pragma unroll
                for (int r2 = 0; r2 < 4; r2++) pk[r2] = f2bf(o_[d4][i][r2] * inv);
                *(us4*)&ctxb[(size_t)qg * EMB + h * HD + 16 * d4 + 4 * quad] = pk;
            }
        }
    } else {
        // partial write: bf16 O + fp32 l
        const int jj = (qi <= 21) ? (qi - 11) * 2 + ch : 22 + (qi - 22) * 3 + ch;
        const int slot = h * SLOTS_PER_HEAD + jj;
        u16* po = pO + (size_t)slot * (128 * 64);
        float* pl = pL + slot * 128;
        #pragma unroll
        for (int i = 0; i < 2; i++) {
            const int qrow = 32 * w + 16 * i + col;
            #pragma unroll
            for (int d4 = 0; d4 < 4; d4++) {
                us4 pk;
                #pragma unroll
                for (int r2 = 0; r2 < 4; r2++) pk[r2] = f2bf(o_[d4][i][r2]);
                *(us4*)&po[(size_t)qrow * 64 + 16 * d4 + 4 * quad] = pk;
            }
            if (quad == 0) pl[qrow] = ol[i][0];
        }
    }
}

// ---------------------------------------------------------------------------
// combine: out[q] = (sum_p O_p[q]) / (sum_p l_p[q]) over a group's 2-3 chunks.
// grid = 16 heads x 21 split q-blocks (qi 11..31) = 336.
// ---------------------------------------------------------------------------
__global__ __launch_bounds__(256)
void combine_kernel(const u16* __restrict__ pO, const float* __restrict__ pL,
                    u16* __restrict__ ctxb) {
    const int g = blockIdx.x;                  // 0..335
    const int h = g / 21, qq = g % 21;
    const int qi = 11 + qq;
    const int nc = (qi <= 21) ? 2 : 3;
    const int jj0 = (qi <= 21) ? (qi - 11) * 2 : 22 + (qi - 22) * 3;
    const int slot0 = h * SLOTS_PER_HEAD + jj0;

    const int t = threadIdx.x;
    const int q = t >> 1, dh = (t & 1) * 32;

    float l = 0.f;
    for (int p = 0; p < nc; p++) l += pL[(slot0 + p) * 128 + q];
    const float inv = 1.0f / l;

    u16* op = ctxb + (size_t)(qi * 128 + q) * EMB + h * HD + dh;

    #pragma unroll
    for (int j = 0; j < 4; j++) {
        float s[8] = {0.f, 0.f, 0.f, 0.f, 0.f, 0.f, 0.f, 0.f};
        for (int p = 0; p < nc; p++) {
            const us8 va = *(const us8*)
                (pO + ((size_t)(slot0 + p) * 128 + q) * 64 + dh + 8 * j);
            #pragma unroll
            for (int e = 0; e < 8; e++) s[e] += bf2f(va[e]);
        }
        us8 vo;
        #pragma unroll
        for (int e = 0; e < 8; e++) vo[e] = f2bf(s[e] * inv);
        *(us8*)(op + 8 * j) = vo;
    }
}

// ---------------------------------------------------------------------------
extern "C" void kernel_launch(void* const* d_in, const int* in_sizes, int n_in,
                              void* d_out, int out_size, void* d_ws, size_t ws_size,
                              hipStream_t stream) {
    const float* x      = (const float*)d_in[0];
    const float* wqkv_w = (const float*)d_in[2];
    const float* wqkv_b = (const float*)d_in[3];
    const float* out_w  = (const float*)d_in[4];
    const float* out_b  = (const float*)d_in[5];
    float* out = (float*)d_out;

    u16* qkvb = (u16*)d_ws;                        // [4096][3072] (V unused)
    u16* ctxb = qkvb + (size_t)S_LEN * E3;         // [4096][1024]
    u16* xb   = ctxb + (size_t)S_LEN * EMB;        // [4096][1024]
    u16* wt   = xb   + (size_t)S_LEN * EMB;        // [3072][1024]
    u16* owt  = wt   + (size_t)E3 * EMB;           // [1024][1024]
    u16* vtb  = owt  + (size_t)EMB * EMB;          // [16][64][4096]

    // flash partials alias the dead contiguous xb+wt span (14.68 MB):
    //   pO: 832 slots x 128x64 bf16 = 13.63 MB, pL: 832x128 f32 = 0.43 MB
    u16*   pO = xb;
    float* pL = (float*)(xb + (size_t)NSLOTS * 128 * 64);

    // RoPE table (1 MB) aliases ctxb: dead until flash writes it, read only
    // by gemm1's epilogue.
    float2* ropetab = (float2*)ctxb;

    dim3 blk(256);

    rope_tab_kernel<<<dim3(S_LEN * 32 / 256), blk, 0, stream>>>(ropetab);
    cast_bf16_kernel<<<dim3(S_LEN * EMB / (256 * 8)), blk, 0, stream>>>(x, xb);
    transpose_cast_kernel<<<dim3(EMB / 64, E3 / 64), blk, 0, stream>>>(
        wqkv_w, wt, EMB, E3);
    transpose_cast_kernel<<<dim3(EMB / 64, EMB / 64), blk, 0, stream>>>(
        out_w, owt, EMB, EMB);

    // QKV projection + fused RoPE (+ q pre-scale) + fused V transpose
    gemm_bt_kernel<1, 4, 1, 3><<<dim3(S_LEN / 128, E3 / 128), blk, 0, stream>>>(
        xb, wt, wqkv_b, qkvb, vtb, ropetab, S_LEN, E3, EMB);

    flash13_kernel<<<dim3(1008), blk, 0, stream>>>(qkvb, vtb, ctxb, pO, pL);
    combine_kernel<<<dim3(336), blk, 0, stream>>>(pO, pL, ctxb);

    // output projection, 128x64 tiles -> 512 blocks (2/CU)
    gemm_bt_kernel<0, 2, 0, 2><<<dim3(S_LEN / 128, EMB / 64), blk, 0, stream>>>(
        ctxb, owt, out_b, out, nullptr, nullptr, S_LEN, EMB, EMB);
}

// Round 5
// 231.351 us; speedup vs baseline: 1.4910x; 1.0652x over previous
//
#include <hip/hip_runtime.h>
#include <hip/hip_bf16.h>
#include <math.h>

#define S_LEN 4096
#define EMB   1024
#define E3    3072
#define NH    16
#define HD    64

// flash partial-combine geometry: qi<=10 direct; qi 11..21 -> 2 chunks;
// qi 22..31 -> 3 chunks.  52 partial slots per head, 832 total.
#define SLOTS_PER_HEAD 52
#define NSLOTS         832

typedef unsigned short u16;
typedef short          bfrag __attribute__((ext_vector_type(8)));  // 8 bf16
typedef float          ffrag __attribute__((ext_vector_type(4)));  // 4 f32
typedef unsigned short us8   __attribute__((ext_vector_type(8)));
typedef unsigned short us4   __attribute__((ext_vector_type(4)));

__device__ __forceinline__ u16 f2bf(float f) {
    union { float f; unsigned u; } v; v.f = f;
    unsigned r = v.u + 0x7fffu + ((v.u >> 16) & 1u);
    return (u16)(r >> 16);
}
__device__ __forceinline__ float bf2f(u16 b) {
    union { unsigned u; float f; } v; v.u = ((unsigned)b) << 16;
    return v.f;
}
// pack two f32 -> two bf16 (truncation) in one v_perm_b32
__device__ __forceinline__ unsigned pack_bf16_trunc(float lo, float hi) {
    union { float f; unsigned u; } a, b; a.f = lo; b.f = hi;
    return __builtin_amdgcn_perm(b.u, a.u, 0x07060302u);
}
// raw v_exp_f32 (2^x).  OCML exp2f adds ~5 fixup ops for subnormals/range;
// softmax doesn't care (subnormal p -> 0 is exact enough; |s| <= ~30 here).
__device__ __forceinline__ float fexp2(float x) {
    float r;
    asm("v_exp_f32 %0, %1" : "=v"(r) : "v"(x));
    return r;
}
// async global->LDS, 16B per lane; LDS dest = uniform base + lane*16
__device__ __forceinline__ void gld16(const void* g, void* l) {
    __builtin_amdgcn_global_load_lds(
        (const __attribute__((address_space(1))) unsigned int*)g,
        (__attribute__((address_space(3))) unsigned int*)l, 16, 0, 0);
}

// ---------------------------------------------------------------------------
// prep: single kernel fusing (launch-gap reduction, bodies unchanged):
//   blocks [0,2048)      : cast x fp32 -> xb bf16 (8 elems/thread)
//   blocks [2048,2816)   : transpose+cast wqkv_w [EMB][E3] -> wt [E3][EMB]
//   blocks [2816,3072)   : transpose+cast out_w  [EMB][EMB] -> owt
//   blocks [3072,3584)   : RoPE table tab[s][j] = (cos,sin)(s*10000^(-j/32))
// ---------------------------------------------------------------------------
__device__ __forceinline__ void transpose_body(const float* __restrict__ in,
                                               u16* __restrict__ out,
                                               int R, int C, int bx, int by,
                                               u16 (*T)[72]) {
    const int r0 = bx * 64, c0 = by * 64;
    const int t = threadIdx.x;
    const int rr = t >> 2, cc = (t & 3) * 16;

    const float* ip = in + (size_t)(r0 + rr) * C + c0 + cc;
    u16 tmp[16];
    #pragma unroll
    for (int i4 = 0; i4 < 4; i4++) {
        float4 v = ((const float4*)ip)[i4];
        tmp[4*i4+0]=f2bf(v.x); tmp[4*i4+1]=f2bf(v.y);
        tmp[4*i4+2]=f2bf(v.z); tmp[4*i4+3]=f2bf(v.w);
    }
    #pragma unroll
    for (int i8 = 0; i8 < 2; i8++) {
        us8 vv;
        #pragma unroll
        for (int j = 0; j < 8; j++) vv[j] = tmp[8*i8+j];
        *(us8*)&T[rr][cc + 8*i8] = vv;
    }
    __syncthreads();

    const int oc = t >> 2, orr = (t & 3) * 16;
    u16 ot[16];
    #pragma unroll
    for (int j = 0; j < 16; j++) ot[j] = T[orr + j][oc];
    u16* op = out + (size_t)(c0 + oc) * R + r0 + orr;
    #pragma unroll
    for (int i8 = 0; i8 < 2; i8++) {
        us8 vv;
        #pragma unroll
        for (int j = 0; j < 8; j++) vv[j] = ot[8*i8+j];
        *(us8*)(op + 8*i8) = vv;
    }
}

__global__ __launch_bounds__(256)
void prep_kernel(const float* __restrict__ x, u16* __restrict__ xb,
                 const float* __restrict__ wqkv_w, u16* __restrict__ wt,
                 const float* __restrict__ out_w, u16* __restrict__ owt,
                 float2* __restrict__ tab) {
    __shared__ u16 T[64][72];
    const int b = blockIdx.x;
    if (b < 2048) {
        const size_t i = ((size_t)b * 256 + threadIdx.x) * 8;
        float4 a = *(const float4*)(x + i);
        float4 c = *(const float4*)(x + i + 4);
        us8 o;
        o[0]=f2bf(a.x); o[1]=f2bf(a.y); o[2]=f2bf(a.z); o[3]=f2bf(a.w);
        o[4]=f2bf(c.x); o[5]=f2bf(c.y); o[6]=f2bf(c.z); o[7]=f2bf(c.w);
        *(us8*)(xb + i) = o;
    } else if (b < 2816) {
        const int bb = b - 2048;
        transpose_body(wqkv_w, wt, EMB, E3, bb & 15, bb >> 4, T);
    } else if (b < 3072) {
        const int bb = b - 2816;
        transpose_body(out_w, owt, EMB, EMB, bb & 15, bb >> 4, T);
    } else {
        const int idx = (b - 3072) * 256 + threadIdx.x;   // s*32 + j
        const int s = idx >> 5, j = idx & 31;
        const float C = 13.287712379549449f / 32.0f;      // log2(10000)/32
        const float invf = exp2f(-(float)j * C);
        float sn, cs;
        sincosf((float)s * invf, &sn, &cs);
        tab[idx] = make_float2(cs, sn);
    }
}

// ---------------------------------------------------------------------------
// bf16 MFMA GEMM, double-buffered: C[M,N] = A[M,K] * Bt[N,K]^T + bias
// Tile 128 x (32*NT); 4 waves as 2m x 2n; wave does 4x NT 16x16x32 tiles.
// ROPE=1 (requires NT=4):
//   n0 <  2048 : fuse RoPE rotation (+0.125*log2e scale for q) -> Cv (qkvb)
//                cos/sin from precomputed table (rope)
//   n0 >= 2048 : V region -- write bias-added values TRANSPOSED to vtp[d][s]
// ---------------------------------------------------------------------------
template <int OUT_BF16, int NT, int ROPE, int MINW>
__global__ __launch_bounds__(256, MINW)
void gemm_bt_kernel(const u16* __restrict__ A, const u16* __restrict__ Bt,
                    const float* __restrict__ bias, void* __restrict__ Cv,
                    u16* __restrict__ vtp, const float2* __restrict__ rope,
                    int M, int N, int K) {
    constexpr int BN = 32 * NT;       // block n-span
    constexpr int WS = 16 * NT;       // wave n-span
    __shared__ u16 As[2][128][32];
    __shared__ u16 Bs[2][BN][32];

    const int tid = threadIdx.x;
    const int w = tid >> 6, L = tid & 63;
    const int col = L & 15, quad = L >> 4;
    const int wm = w & 1, wn = w >> 1;
    const int m0 = blockIdx.x * 128, n0 = blockIdx.y * BN;

    ffrag acc[4][NT];
    #pragma unroll
    for (int a = 0; a < 4; a++)
        #pragma unroll
        for (int b = 0; b < NT; b++)
            #pragma unroll
            for (int r = 0; r < 4; r++) acc[a][b][r] = 0.f;

    const int srow = L >> 2;
    const int schk = L & 3;

    // prologue: stage k=0 into buf 0
    #pragma unroll
    for (int t = 0; t < 2; t++) {
        const int rg = (2 * w + t) * 16;
        gld16(A + (size_t)(m0 + rg + srow) * K + schk * 8, &As[0][rg][0]);
    }
    #pragma unroll
    for (int t = 0; t < NT / 2; t++) {
        const int rg = (w * (NT / 2) + t) * 16;
        gld16(Bt + (size_t)(n0 + rg + srow) * K + schk * 8, &Bs[0][rg][0]);
    }
    __syncthreads();

    int buf = 0;
    for (int k0 = 0; k0 < K; k0 += 32, buf ^= 1) {
        if (k0 + 32 < K) {
            #pragma unroll
            for (int t = 0; t < 2; t++) {
                const int rg = (2 * w + t) * 16;
                gld16(A + (size_t)(m0 + rg + srow) * K + k0 + 32 + schk * 8,
                      &As[buf ^ 1][rg][0]);
            }
            #pragma unroll
            for (int t = 0; t < NT / 2; t++) {
                const int rg = (w * (NT / 2) + t) * 16;
                gld16(Bt + (size_t)(n0 + rg + srow) * K + k0 + 32 + schk * 8,
                      &Bs[buf ^ 1][rg][0]);
            }
        }

        bfrag af[4], bf[NT];
        #pragma unroll
        for (int mt = 0; mt < 4; mt++)
            af[mt] = *(const bfrag*)&As[buf][64 * wm + 16 * mt + col][8 * quad];
        #pragma unroll
        for (int nt = 0; nt < NT; nt++)
            bf[nt] = *(const bfrag*)&Bs[buf][WS * wn + 16 * nt + col][8 * quad];
        #pragma unroll
        for (int mt = 0; mt < 4; mt++)
            #pragma unroll
            for (int nt = 0; nt < NT; nt++)
                acc[mt][nt] = __builtin_amdgcn_mfma_f32_16x16x32_bf16(
                    af[mt], bf[nt], acc[mt][nt], 0, 0, 0);

        __syncthreads();
    }

    float bv[NT];
    #pragma unroll
    for (int nt = 0; nt < NT; nt++) bv[nt] = bias[n0 + WS * wn + 16 * nt + col];

    if (ROPE && n0 < 2 * EMB) {
        // q (n<1024) or k (1024..2047): rotate (d, d+32) pairs, table lookup.
        const float SCq = (n0 < EMB) ? 0.125f * 1.44269504088896f : 1.0f;
        #pragma unroll
        for (int mt = 0; mt < 4; mt++) {
            #pragma unroll
            for (int r = 0; r < 4; r++) {
                const int mrow = m0 + 64 * wm + 16 * mt + 4 * quad + r;
                u16* cp = (u16*)Cv + (size_t)mrow * N + n0 + 64 * wn + col;
                #pragma unroll
                for (int pr = 0; pr < 2; pr++) {
                    const float2 t = rope[(size_t)mrow * 32 + col + 16 * pr];
                    const float cs = t.x, sn = t.y;
                    const float t1 = acc[mt][pr][r] + bv[pr];
                    const float t2 = acc[mt][pr + 2][r] + bv[pr + 2];
                    cp[16 * pr]      = f2bf((t1 * cs - t2 * sn) * SCq);
                    cp[16 * pr + 32] = f2bf((t2 * cs + t1 * sn) * SCq);
                }
            }
        }
    } else if (ROPE) {
        // V region: write transposed to vtp[d][s], d = n - 2048.
        #pragma unroll
        for (int nt = 0; nt < NT; nt++) {
            const int dg = n0 - 2 * EMB + WS * wn + 16 * nt + col;
            #pragma unroll
            for (int mt = 0; mt < 4; mt++) {
                const int s0 = m0 + 64 * wm + 16 * mt + 4 * quad;
                us4 pk;
                #pragma unroll
                for (int r = 0; r < 4; r++) pk[r] = f2bf(acc[mt][nt][r] + bv[nt]);
                *(us4*)&vtp[(size_t)dg * S_LEN + s0] = pk;
            }
        }
    } else {
        #pragma unroll
        for (int mt = 0; mt < 4; mt++) {
            #pragma unroll
            for (int r = 0; r < 4; r++) {
                const int m = m0 + 64 * wm + 16 * mt + 4 * quad + r;
                #pragma unroll
                for (int nt = 0; nt < NT; nt++) {
                    const int n = n0 + WS * wn + 16 * nt + col;
                    const float val = acc[mt][nt][r] + bv[nt];
                    if (OUT_BF16) ((u16*)Cv)[(size_t)m * N + n] = f2bf(val);
                    else          ((float*)Cv)[(size_t)m * N + n] = val;
                }
            }
        }
    }
}

// ---------------------------------------------------------------------------
// flash14: flash13 structure (K/V double-buffered LDS, 48 KB, 3 blocks/CU,
// VGPR 68 -- the no-spill ceiling established in rounds 2/3), issue-count
// reduction:
//   - raw v_exp_f32 instead of OCML exp2f (~5 fewer VALU ops per exp, 32/tile)
//   - QK^T ks=0 uses a zero C operand: kills 32 accumulator-init writes/tile
//   - setprio removed (round-4 A/B: null to slightly negative)
// Schedule: qi<=10 direct; qi 11..21 2 chunks; qi 22..31 3 chunks;
// 1008 blocks, longest-first per XCD lane, id&7 = XCD, 2 heads/XCD.
// ---------------------------------------------------------------------------
__global__ __launch_bounds__(256, 3)
void flash14_kernel(const u16* __restrict__ qkvb, const u16* __restrict__ vt,
                    u16* __restrict__ ctxb, u16* __restrict__ pO,
                    float* __restrict__ pL) {
    __shared__ u16 QP[4][32][64];     // per-wave: Q rows, then P overlay
    __shared__ u16 Ks[2][64][64];
    __shared__ u16 Vs[2][64][64];

    const int id = blockIdx.x;                    // 0..1007
    const int x  = id & 7;                        // XCD
    const int tt = id >> 3;                       // 0..125
    const int h  = x + 8 * (tt & 1);              // 2 heads per XCD, interleaved
    const int o  = tt >> 1;                       // 0..62 order index, long-first

    int qi, ch, nc;
    if (o < 30)      { qi = 31 - o / 3;        ch = o % 3;        nc = 3; }
    else if (o < 33) { qi = 10 - (o - 30);     ch = 0;            nc = 1; }
    else if (o < 55) { const int oo = o - 33;  qi = 21 - oo / 2;  ch = oo & 1; nc = 2; }
    else             { qi = 7 - (o - 55);      ch = 0;            nc = 1; }

    const int total = 2 * qi + 2;
    const int Lc    = (total + nc - 1) / nc;
    const int kt0   = ch * Lc;
    const int cnt   = min(Lc, total - kt0);
    const bool lastch = (kt0 + cnt == total);     // chunk holding the diagonal
    const int q0 = qi * 128;

    const int tid = threadIdx.x;
    const int w = tid >> 6, L = tid & 63;
    const int col = L & 15, quad = L >> 4;
    const int lr = L >> 3, lp = L & 7;
    const int lc = lp ^ lr;                       // swizzled chunk for staging

    const bool domask = lastch;
    const int nwt = cnt - ((domask && w < 2) ? 1 : 0);

    const size_t kArow = (size_t)(16 * w + lr) * E3 + EMB + h * HD + lc * 8;
    const size_t vArow = ((size_t)h * HD + 16 * w + lr) * S_LEN + lc * 8;
    const size_t kt0off  = (size_t)kt0 * 64 * E3;
    const size_t vt0off  = (size_t)kt0 * 64;

    // ---- stage Q (own wave's 32 rows) + K/V tile kt0 ----
    #pragma unroll
    for (int u = 0; u < 4; u++)
        gld16(qkvb + (size_t)(q0 + 32 * w + 8 * u + lr) * E3 + h * HD + lc * 8,
              &QP[w][8 * u][0]);
    #pragma unroll
    for (int u = 0; u < 2; u++) {
        gld16(qkvb + kArow + kt0off + (size_t)(8 * u) * E3,
              &Ks[0][16 * w + 8 * u][0]);
        gld16(vt + vArow + vt0off + (size_t)(8 * u) * S_LEN,
              &Vs[0][16 * w + 8 * u][0]);
    }
    __syncthreads();

    bfrag qf[2][2];
    #pragma unroll
    for (int i = 0; i < 2; i++)
        #pragma unroll
        for (int ks = 0; ks < 2; ks++)
            qf[i][ks] = *(const bfrag*)
                ((const char*)&QP[w][16 * i + col][0] +
                 16 * ((4 * ks + quad) ^ (col & 7)));

    bfrag ones;
    #pragma unroll
    for (int i = 0; i < 8; i++) ones[i] = (short)0x3F80;
    const ffrag zf = {0.f, 0.f, 0.f, 0.f};

    ffrag o_[4][2], ol[2];
    #pragma unroll
    for (int d4 = 0; d4 < 4; d4++)
        #pragma unroll
        for (int i = 0; i < 2; i++)
            #pragma unroll
            for (int r2 = 0; r2 < 4; r2++) o_[d4][i][r2] = 0.f;
    #pragma unroll
    for (int i = 0; i < 2; i++)
        #pragma unroll
        for (int r2 = 0; r2 < 4; r2++) ol[i][r2] = 0.f;

    #pragma unroll 1
    for (int t = 0; t < cnt; t++) {
        const int buf = t & 1;
        // prefetch next k-tile into the other buffer (before compute)
        if (t + 1 < cnt) {
            const size_t ko = kArow + kt0off + (size_t)(t + 1) * 64 * E3;
            const size_t vo = vArow + vt0off + (size_t)(t + 1) * 64;
            #pragma unroll
            for (int u = 0; u < 2; u++) {
                gld16(qkvb + ko + (size_t)(8 * u) * E3,
                      &Ks[buf ^ 1][16 * w + 8 * u][0]);
                gld16(vt + vo + (size_t)(8 * u) * S_LEN,
                      &Vs[buf ^ 1][16 * w + 8 * u][0]);
            }
        }

        if (t < nwt) {
            // ---- S^T = K Q^T ----
            ffrag st[4][2];
            bfrag kf[4];
            // ks = 0: C = zero (no accumulator pre-init needed)
            #pragma unroll
            for (int t4 = 0; t4 < 4; t4++)
                kf[t4] = *(const bfrag*)
                    &Ks[buf][16 * t4 + col][((quad ^ (col & 7)) * 8)];
            #pragma unroll
            for (int t4 = 0; t4 < 4; t4++)
                #pragma unroll
                for (int i = 0; i < 2; i++)
                    st[t4][i] = __builtin_amdgcn_mfma_f32_16x16x32_bf16(
                        kf[t4], qf[i][0], zf, 0, 0, 0);
            // ks = 1: accumulate
            #pragma unroll
            for (int t4 = 0; t4 < 4; t4++)
                kf[t4] = *(const bfrag*)
                    &Ks[buf][16 * t4 + col][(((4 + quad) ^ (col & 7)) * 8)];
            #pragma unroll
            for (int t4 = 0; t4 < 4; t4++)
                #pragma unroll
                for (int i = 0; i < 2; i++)
                    st[t4][i] = __builtin_amdgcn_mfma_f32_16x16x32_bf16(
                        kf[t4], qf[i][1], st[t4][i], 0, 0, 0);

            // ---- causal mask: only this wave's diagonal tile ----
            if (domask && t == nwt - 1) {
                #pragma unroll
                for (int i = 0; i < 2; i++) {
                    const int qrel = 32 * (w & 1) + 16 * i + col;
                    #pragma unroll
                    for (int t4 = 0; t4 < 4; t4++) {
                        const int key0 = 16 * t4 + 4 * quad;
                        #pragma unroll
                        for (int r2 = 0; r2 < 4; r2++)
                            if (key0 + r2 > qrel) st[t4][i][r2] = -3.0e38f;
                    }
                }
            }

            // ---- softmax numerator: p = exp2(s), no shift ----
            #pragma unroll
            for (int i = 0; i < 2; i++) {
                const int prow = 16 * i + col;
                #pragma unroll
                for (int t4 = 0; t4 < 4; t4++) {
                    float pr[4];
                    #pragma unroll
                    for (int r2 = 0; r2 < 4; r2++) pr[r2] = fexp2(st[t4][i][r2]);
                    uint2 pk;
                    pk.x = pack_bf16_trunc(pr[0], pr[1]);
                    pk.y = pack_bf16_trunc(pr[2], pr[3]);
                    const int c2 = (2 * t4 + (quad >> 1)) ^ (col & 7);
                    *(uint2*)((char*)&QP[w][prow][0] + 16 * c2 + 8 * (quad & 1)) = pk;
                }
            }

            // ---- O^T += V^T P^T ;  l += 1^T P^T ----
            #pragma unroll
            for (int ks = 0; ks < 2; ks++) {
                bfrag vf[4];
                #pragma unroll
                for (int d4 = 0; d4 < 4; d4++)
                    vf[d4] = *(const bfrag*)
                        &Vs[buf][16 * d4 + col][(((4 * ks + quad) ^ (col & 7)) * 8)];
                bfrag pf[2];
                #pragma unroll
                for (int i = 0; i < 2; i++)
                    pf[i] = *(const bfrag*)
                        ((const char*)&QP[w][16 * i + col][0] +
                         16 * ((4 * ks + quad) ^ (col & 7)));
                #pragma unroll
                for (int d4 = 0; d4 < 4; d4++)
                    #pragma unroll
                    for (int i = 0; i < 2; i++)
                        o_[d4][i] = __builtin_amdgcn_mfma_f32_16x16x32_bf16(
                            vf[d4], pf[i], o_[d4][i], 0, 0, 0);
                #pragma unroll
                for (int i = 0; i < 2; i++)
                    ol[i] = __builtin_amdgcn_mfma_f32_16x16x32_bf16(
                        ones, pf[i], ol[i], 0, 0, 0);
            }
        }

        __syncthreads();   // compute done; next tile's loads drained here
    }

    // ---- epilogue ----
    if (nc == 1) {
        // direct normalized write
        #pragma unroll
        for (int i = 0; i < 2; i++) {
            const float inv = 1.0f / ol[i][0];
            const int qg = q0 + 32 * w + 16 * i + col;
            #pragma unroll
            for (int d4 = 0; d4 < 4; d4++) {
                us4 pk;
                #pragma unroll
                for (int r2 = 0; r2 < 4; r2++) pk[r2] = f2bf(o_[d4][i][r2] * inv);
                *(us4*)&ctxb[(size_t)qg * EMB + h * HD + 16 * d4 + 4 * quad] = pk;
            }
        }
    } else {
        // partial write: bf16 O + fp32 l
        const int jj = (qi <= 21) ? (qi - 11) * 2 + ch : 22 + (qi - 22) * 3 + ch;
        const int slot = h * SLOTS_PER_HEAD + jj;
        u16* po = pO + (size_t)slot * (128 * 64);
        float* pl = pL + slot * 128;
        #pragma unroll
        for (int i = 0; i < 2; i++) {
            const int qrow = 32 * w + 16 * i + col;
            #pragma unroll
            for (int d4 = 0; d4 < 4; d4++) {
                us4 pk;
                #pragma unroll
                for (int r2 = 0; r2 < 4; r2++) pk[r2] = f2bf(o_[d4][i][r2]);
                *(us4*)&po[(size_t)qrow * 64 + 16 * d4 + 4 * quad] = pk;
            }
            if (quad == 0) pl[qrow] = ol[i][0];
        }
    }
}

// ---------------------------------------------------------------------------
// combine: out[q] = (sum_p O_p[q]) / (sum_p l_p[q]) over a group's 2-3 chunks.
// grid = 16 heads x 21 split q-blocks (qi 11..31) = 336.
// ---------------------------------------------------------------------------
__global__ __launch_bounds__(256)
void combine_kernel(const u16* __restrict__ pO, const float* __restrict__ pL,
                    u16* __restrict__ ctxb) {
    const int g = blockIdx.x;                  // 0..335
    const int h = g / 21, qq = g % 21;
    const int qi = 11 + qq;
    const int nc = (qi <= 21) ? 2 : 3;
    const int jj0 = (qi <= 21) ? (qi - 11) * 2 : 22 + (qi - 22) * 3;
    const int slot0 = h * SLOTS_PER_HEAD + jj0;

    const int t = threadIdx.x;
    const int q = t >> 1, dh = (t & 1) * 32;

    float l = 0.f;
    for (int p = 0; p < nc; p++) l += pL[(slot0 + p) * 128 + q];
    const float inv = 1.0f / l;

    u16* op = ctxb + (size_t)(qi * 128 + q) * EMB + h * HD + dh;

    #pragma unroll
    for (int j = 0; j < 4; j++) {
        float s[8] = {0.f, 0.f, 0.f, 0.f, 0.f, 0.f, 0.f, 0.f};
        for (int p = 0; p < nc; p++) {
            const us8 va = *(const us8*)
                (pO + ((size_t)(slot0 + p) * 128 + q) * 64 + dh + 8 * j);
            #pragma unroll
            for (int e = 0; e < 8; e++) s[e] += bf2f(va[e]);
        }
        us8 vo;
        #pragma unroll
        for (int e = 0; e < 8; e++) vo[e] = f2bf(s[e] * inv);
        *(us8*)(op + 8 * j) = vo;
    }
}

// ---------------------------------------------------------------------------
extern "C" void kernel_launch(void* const* d_in, const int* in_sizes, int n_in,
                              void* d_out, int out_size, void* d_ws, size_t ws_size,
                              hipStream_t stream) {
    const float* x      = (const float*)d_in[0];
    const float* wqkv_w = (const float*)d_in[2];
    const float* wqkv_b = (const float*)d_in[3];
    const float* out_w  = (const float*)d_in[4];
    const float* out_b  = (const float*)d_in[5];
    float* out = (float*)d_out;

    u16* qkvb = (u16*)d_ws;                        // [4096][3072] (V unused)
    u16* ctxb = qkvb + (size_t)S_LEN * E3;         // [4096][1024]
    u16* xb   = ctxb + (size_t)S_LEN * EMB;        // [4096][1024]
    u16* wt   = xb   + (size_t)S_LEN * EMB;        // [3072][1024]
    u16* owt  = wt   + (size_t)E3 * EMB;           // [1024][1024]
    u16* vtb  = owt  + (size_t)EMB * EMB;          // [16][64][4096]

    // flash partials alias the dead contiguous xb+wt span (14.68 MB):
    //   pO: 832 slots x 128x64 bf16 = 13.63 MB, pL: 832x128 f32 = 0.43 MB
    u16*   pO = xb;
    float* pL = (float*)(xb + (size_t)NSLOTS * 128 * 64);

    // RoPE table (1 MB) aliases ctxb: dead until flash writes it, read only
    // by gemm1's epilogue.
    float2* ropetab = (float2*)ctxb;

    dim3 blk(256);

    // fused preprocessing: cast + 2 transposes + rope table (1 launch)
    prep_kernel<<<dim3(3584), blk, 0, stream>>>(
        x, xb, wqkv_w, wt, out_w, owt, ropetab);

    // QKV projection + fused RoPE (+ q pre-scale) + fused V transpose
    gemm_bt_kernel<1, 4, 1, 3><<<dim3(S_LEN / 128, E3 / 128), blk, 0, stream>>>(
        xb, wt, wqkv_b, qkvb, vtb, ropetab, S_LEN, E3, EMB);

    flash14_kernel<<<dim3(1008), blk, 0, stream>>>(qkvb, vtb, ctxb, pO, pL);
    combine_kernel<<<dim3(336), blk, 0, stream>>>(pO, pL, ctxb);

    // output projection, 128x64 tiles -> 512 blocks (2/CU)
    gemm_bt_kernel<0, 2, 0, 2><<<dim3(S_LEN / 128, EMB / 64), blk, 0, stream>>>(
        ctxb, owt, out_b, out, nullptr, nullptr, S_LEN, EMB, EMB);
}

// Round 6
// 230.400 us; speedup vs baseline: 1.4971x; 1.0041x over previous
//
#include <hip/hip_runtime.h>
#include <hip/hip_bf16.h>
#include <math.h>

#define S_LEN 4096
#define EMB   1024
#define E3    3072
#define NH    16
#define HD    64

// flash partial-combine geometry: qi<=10 direct; qi 11..21 -> 2 chunks;
// qi 22..31 -> 3 chunks.  52 partial slots per head, 832 total.
#define SLOTS_PER_HEAD 52
#define NSLOTS         832

typedef unsigned short u16;
typedef short          bfrag __attribute__((ext_vector_type(8)));  // 8 bf16
typedef float          ffrag __attribute__((ext_vector_type(4)));  // 4 f32
typedef unsigned short us8   __attribute__((ext_vector_type(8)));
typedef unsigned short us4   __attribute__((ext_vector_type(4)));

__device__ __forceinline__ u16 f2bf(float f) {
    union { float f; unsigned u; } v; v.f = f;
    unsigned r = v.u + 0x7fffu + ((v.u >> 16) & 1u);
    return (u16)(r >> 16);
}
__device__ __forceinline__ float bf2f(u16 b) {
    union { unsigned u; float f; } v; v.u = ((unsigned)b) << 16;
    return v.f;
}
// pack two f32 -> two bf16 (truncation) in one v_perm_b32
__device__ __forceinline__ unsigned pack_bf16_trunc(float lo, float hi) {
    union { float f; unsigned u; } a, b; a.f = lo; b.f = hi;
    return __builtin_amdgcn_perm(b.u, a.u, 0x07060302u);
}
// raw v_exp_f32 (2^x).  OCML exp2f adds ~5 fixup ops for subnormals/range;
// softmax doesn't care (subnormal p -> 0 is exact enough; |s| <= ~30 here).
__device__ __forceinline__ float fexp2(float x) {
    float r;
    asm("v_exp_f32 %0, %1" : "=v"(r) : "v"(x));
    return r;
}
// async global->LDS, 16B per lane; LDS dest = uniform base + lane*16
__device__ __forceinline__ void gld16(const void* g, void* l) {
    __builtin_amdgcn_global_load_lds(
        (const __attribute__((address_space(1))) unsigned int*)g,
        (__attribute__((address_space(3))) unsigned int*)l, 16, 0, 0);
}

// ---------------------------------------------------------------------------
// prep: single kernel fusing (launch-gap reduction, bodies unchanged):
//   blocks [0,2048)      : cast x fp32 -> xb bf16 (8 elems/thread)
//   blocks [2048,2816)   : transpose+cast wqkv_w [EMB][E3] -> wt [E3][EMB]
//   blocks [2816,3072)   : transpose+cast out_w  [EMB][EMB] -> owt
//   blocks [3072,3584)   : RoPE table tab[s][j] = (cos,sin)(s*10000^(-j/32))
// ---------------------------------------------------------------------------
__device__ __forceinline__ void transpose_body(const float* __restrict__ in,
                                               u16* __restrict__ out,
                                               int R, int C, int bx, int by,
                                               u16 (*T)[72]) {
    const int r0 = bx * 64, c0 = by * 64;
    const int t = threadIdx.x;
    const int rr = t >> 2, cc = (t & 3) * 16;

    const float* ip = in + (size_t)(r0 + rr) * C + c0 + cc;
    u16 tmp[16];
    #pragma unroll
    for (int i4 = 0; i4 < 4; i4++) {
        float4 v = ((const float4*)ip)[i4];
        tmp[4*i4+0]=f2bf(v.x); tmp[4*i4+1]=f2bf(v.y);
        tmp[4*i4+2]=f2bf(v.z); tmp[4*i4+3]=f2bf(v.w);
    }
    #pragma unroll
    for (int i8 = 0; i8 < 2; i8++) {
        us8 vv;
        #pragma unroll
        for (int j = 0; j < 8; j++) vv[j] = tmp[8*i8+j];
        *(us8*)&T[rr][cc + 8*i8] = vv;
    }
    __syncthreads();

    const int oc = t >> 2, orr = (t & 3) * 16;
    u16 ot[16];
    #pragma unroll
    for (int j = 0; j < 16; j++) ot[j] = T[orr + j][oc];
    u16* op = out + (size_t)(c0 + oc) * R + r0 + orr;
    #pragma unroll
    for (int i8 = 0; i8 < 2; i8++) {
        us8 vv;
        #pragma unroll
        for (int j = 0; j < 8; j++) vv[j] = ot[8*i8+j];
        *(us8*)(op + 8*i8) = vv;
    }
}

__global__ __launch_bounds__(256)
void prep_kernel(const float* __restrict__ x, u16* __restrict__ xb,
                 const float* __restrict__ wqkv_w, u16* __restrict__ wt,
                 const float* __restrict__ out_w, u16* __restrict__ owt,
                 float2* __restrict__ tab) {
    __shared__ u16 T[64][72];
    const int b = blockIdx.x;
    if (b < 2048) {
        const size_t i = ((size_t)b * 256 + threadIdx.x) * 8;
        float4 a = *(const float4*)(x + i);
        float4 c = *(const float4*)(x + i + 4);
        us8 o;
        o[0]=f2bf(a.x); o[1]=f2bf(a.y); o[2]=f2bf(a.z); o[3]=f2bf(a.w);
        o[4]=f2bf(c.x); o[5]=f2bf(c.y); o[6]=f2bf(c.z); o[7]=f2bf(c.w);
        *(us8*)(xb + i) = o;
    } else if (b < 2816) {
        const int bb = b - 2048;
        transpose_body(wqkv_w, wt, EMB, E3, bb & 15, bb >> 4, T);
    } else if (b < 3072) {
        const int bb = b - 2816;
        transpose_body(out_w, owt, EMB, EMB, bb & 15, bb >> 4, T);
    } else {
        const int idx = (b - 3072) * 256 + threadIdx.x;   // s*32 + j
        const int s = idx >> 5, j = idx & 31;
        const float C = 13.287712379549449f / 32.0f;      // log2(10000)/32
        const float invf = exp2f(-(float)j * C);
        float sn, cs;
        sincosf((float)s * invf, &sn, &cs);
        tab[idx] = make_float2(cs, sn);
    }
}

// ---------------------------------------------------------------------------
// bf16 MFMA GEMM, double-buffered: C[M,N] = A[M,K] * Bt[N,K]^T + bias
// Tile 128 x (32*NT); 4 waves as 2m x 2n; wave does 4x NT 16x16x32 tiles.
// ROPE=1 (requires NT=4):
//   n0 <  2048 : fuse RoPE rotation (+0.125*log2e scale for q) -> Cv (qkvb)
//                cos/sin from precomputed table (rope)
//   n0 >= 2048 : V region -- write bias-added values TRANSPOSED to vtp[d][s]
// ---------------------------------------------------------------------------
template <int OUT_BF16, int NT, int ROPE, int MINW>
__global__ __launch_bounds__(256, MINW)
void gemm_bt_kernel(const u16* __restrict__ A, const u16* __restrict__ Bt,
                    const float* __restrict__ bias, void* __restrict__ Cv,
                    u16* __restrict__ vtp, const float2* __restrict__ rope,
                    int M, int N, int K) {
    constexpr int BN = 32 * NT;       // block n-span
    constexpr int WS = 16 * NT;       // wave n-span
    __shared__ u16 As[2][128][32];
    __shared__ u16 Bs[2][BN][32];

    const int tid = threadIdx.x;
    const int w = tid >> 6, L = tid & 63;
    const int col = L & 15, quad = L >> 4;
    const int wm = w & 1, wn = w >> 1;
    const int m0 = blockIdx.x * 128, n0 = blockIdx.y * BN;

    ffrag acc[4][NT];
    #pragma unroll
    for (int a = 0; a < 4; a++)
        #pragma unroll
        for (int b = 0; b < NT; b++)
            #pragma unroll
            for (int r = 0; r < 4; r++) acc[a][b][r] = 0.f;

    const int srow = L >> 2;
    const int schk = L & 3;

    // prologue: stage k=0 into buf 0
    #pragma unroll
    for (int t = 0; t < 2; t++) {
        const int rg = (2 * w + t) * 16;
        gld16(A + (size_t)(m0 + rg + srow) * K + schk * 8, &As[0][rg][0]);
    }
    #pragma unroll
    for (int t = 0; t < NT / 2; t++) {
        const int rg = (w * (NT / 2) + t) * 16;
        gld16(Bt + (size_t)(n0 + rg + srow) * K + schk * 8, &Bs[0][rg][0]);
    }
    __syncthreads();

    int buf = 0;
    for (int k0 = 0; k0 < K; k0 += 32, buf ^= 1) {
        if (k0 + 32 < K) {
            #pragma unroll
            for (int t = 0; t < 2; t++) {
                const int rg = (2 * w + t) * 16;
                gld16(A + (size_t)(m0 + rg + srow) * K + k0 + 32 + schk * 8,
                      &As[buf ^ 1][rg][0]);
            }
            #pragma unroll
            for (int t = 0; t < NT / 2; t++) {
                const int rg = (w * (NT / 2) + t) * 16;
                gld16(Bt + (size_t)(n0 + rg + srow) * K + k0 + 32 + schk * 8,
                      &Bs[buf ^ 1][rg][0]);
            }
        }

        bfrag af[4], bf[NT];
        #pragma unroll
        for (int mt = 0; mt < 4; mt++)
            af[mt] = *(const bfrag*)&As[buf][64 * wm + 16 * mt + col][8 * quad];
        #pragma unroll
        for (int nt = 0; nt < NT; nt++)
            bf[nt] = *(const bfrag*)&Bs[buf][WS * wn + 16 * nt + col][8 * quad];
        #pragma unroll
        for (int mt = 0; mt < 4; mt++)
            #pragma unroll
            for (int nt = 0; nt < NT; nt++)
                acc[mt][nt] = __builtin_amdgcn_mfma_f32_16x16x32_bf16(
                    af[mt], bf[nt], acc[mt][nt], 0, 0, 0);

        __syncthreads();
    }

    float bv[NT];
    #pragma unroll
    for (int nt = 0; nt < NT; nt++) bv[nt] = bias[n0 + WS * wn + 16 * nt + col];

    if (ROPE && n0 < 2 * EMB) {
        // q (n<1024) or k (1024..2047): rotate (d, d+32) pairs, table lookup.
        const float SCq = (n0 < EMB) ? 0.125f * 1.44269504088896f : 1.0f;
        #pragma unroll
        for (int mt = 0; mt < 4; mt++) {
            #pragma unroll
            for (int r = 0; r < 4; r++) {
                const int mrow = m0 + 64 * wm + 16 * mt + 4 * quad + r;
                u16* cp = (u16*)Cv + (size_t)mrow * N + n0 + 64 * wn + col;
                #pragma unroll
                for (int pr = 0; pr < 2; pr++) {
                    const float2 t = rope[(size_t)mrow * 32 + col + 16 * pr];
                    const float cs = t.x, sn = t.y;
                    const float t1 = acc[mt][pr][r] + bv[pr];
                    const float t2 = acc[mt][pr + 2][r] + bv[pr + 2];
                    cp[16 * pr]      = f2bf((t1 * cs - t2 * sn) * SCq);
                    cp[16 * pr + 32] = f2bf((t2 * cs + t1 * sn) * SCq);
                }
            }
        }
    } else if (ROPE) {
        // V region: write transposed to vtp[d][s], d = n - 2048.
        #pragma unroll
        for (int nt = 0; nt < NT; nt++) {
            const int dg = n0 - 2 * EMB + WS * wn + 16 * nt + col;
            #pragma unroll
            for (int mt = 0; mt < 4; mt++) {
                const int s0 = m0 + 64 * wm + 16 * mt + 4 * quad;
                us4 pk;
                #pragma unroll
                for (int r = 0; r < 4; r++) pk[r] = f2bf(acc[mt][nt][r] + bv[nt]);
                *(us4*)&vtp[(size_t)dg * S_LEN + s0] = pk;
            }
        }
    } else {
        #pragma unroll
        for (int mt = 0; mt < 4; mt++) {
            #pragma unroll
            for (int r = 0; r < 4; r++) {
                const int m = m0 + 64 * wm + 16 * mt + 4 * quad + r;
                #pragma unroll
                for (int nt = 0; nt < NT; nt++) {
                    const int n = n0 + WS * wn + 16 * nt + col;
                    const float val = acc[mt][nt][r] + bv[nt];
                    if (OUT_BF16) ((u16*)Cv)[(size_t)m * N + n] = f2bf(val);
                    else          ((float*)Cv)[(size_t)m * N + n] = val;
                }
            }
        }
    }
}

// ---------------------------------------------------------------------------
// flash15: flash14 body (fexp2, zero-C QK) + flash12's 2-barrier
// SINGLE-buffered K/V (structure verified correct in round 3; its 344us was
// a spill artifact of MINW=5's 102-reg cap, NOT the barrier scheme).
// Per tile:  QK^T(Ks) -> softmax -> B1 (drains V[t] issued after prev B2)
//            -> issue K[t+1] -> PV(Vs) -> B2 (drains K[t+1]) -> issue V[t+1]
// LDS 16 QP + 8 Ks + 8 Vs = 32 KB -> 4 blocks/CU (16 waves, +33% vs flash14's
// 3).  MINW=4 -> reg cap 128 >> the ~68 this body needs: spill-proof
// (round-3 lesson; if VGPR_Count drops below ~68 or WRITE_SIZE balloons,
// the compiler spilled and this change must be reverted).
// Schedule: qi<=10 direct; qi 11..21 2 chunks; qi 22..31 3 chunks;
// 1008 blocks, longest-first per XCD lane, id&7 = XCD, 2 heads/XCD.
// ---------------------------------------------------------------------------
__global__ __launch_bounds__(256, 4)
void flash15_kernel(const u16* __restrict__ qkvb, const u16* __restrict__ vt,
                    u16* __restrict__ ctxb, u16* __restrict__ pO,
                    float* __restrict__ pL) {
    __shared__ u16 QP[4][32][64];     // per-wave: Q rows, then P overlay
    __shared__ u16 Ks[64][64];
    __shared__ u16 Vs[64][64];

    const int id = blockIdx.x;                    // 0..1007
    const int x  = id & 7;                        // XCD
    const int tt = id >> 3;                       // 0..125
    const int h  = x + 8 * (tt & 1);              // 2 heads per XCD, interleaved
    const int o  = tt >> 1;                       // 0..62 order index, long-first

    int qi, ch, nc;
    if (o < 30)      { qi = 31 - o / 3;        ch = o % 3;        nc = 3; }
    else if (o < 33) { qi = 10 - (o - 30);     ch = 0;            nc = 1; }
    else if (o < 55) { const int oo = o - 33;  qi = 21 - oo / 2;  ch = oo & 1; nc = 2; }
    else             { qi = 7 - (o - 55);      ch = 0;            nc = 1; }

    const int total = 2 * qi + 2;
    const int Lc    = (total + nc - 1) / nc;
    const int kt0   = ch * Lc;
    const int cnt   = min(Lc, total - kt0);
    const bool lastch = (kt0 + cnt == total);     // chunk holding the diagonal
    const int q0 = qi * 128;

    const int tid = threadIdx.x;
    const int w = tid >> 6, L = tid & 63;
    const int col = L & 15, quad = L >> 4;
    const int lr = L >> 3, lp = L & 7;
    const int lc = lp ^ lr;                       // swizzled chunk for staging

    const bool domask = lastch;
    const int nwt = cnt - ((domask && w < 2) ? 1 : 0);

    const size_t kArow = (size_t)(16 * w + lr) * E3 + EMB + h * HD + lc * 8;
    const size_t vArow = ((size_t)h * HD + 16 * w + lr) * S_LEN + lc * 8;
    const size_t kt0off  = (size_t)kt0 * 64 * E3;
    const size_t vt0off  = (size_t)kt0 * 64;

    // ---- stage Q (own wave's 32 rows) + K/V tile kt0 ----
    #pragma unroll
    for (int u = 0; u < 4; u++)
        gld16(qkvb + (size_t)(q0 + 32 * w + 8 * u + lr) * E3 + h * HD + lc * 8,
              &QP[w][8 * u][0]);
    #pragma unroll
    for (int u = 0; u < 2; u++) {
        gld16(qkvb + kArow + kt0off + (size_t)(8 * u) * E3,
              &Ks[16 * w + 8 * u][0]);
        gld16(vt + vArow + vt0off + (size_t)(8 * u) * S_LEN,
              &Vs[16 * w + 8 * u][0]);
    }
    __syncthreads();

    bfrag qf[2][2];
    #pragma unroll
    for (int i = 0; i < 2; i++)
        #pragma unroll
        for (int ks = 0; ks < 2; ks++)
            qf[i][ks] = *(const bfrag*)
                ((const char*)&QP[w][16 * i + col][0] +
                 16 * ((4 * ks + quad) ^ (col & 7)));

    bfrag ones;
    #pragma unroll
    for (int i = 0; i < 8; i++) ones[i] = (short)0x3F80;
    const ffrag zf = {0.f, 0.f, 0.f, 0.f};

    ffrag o_[4][2], ol[2];
    #pragma unroll
    for (int d4 = 0; d4 < 4; d4++)
        #pragma unroll
        for (int i = 0; i < 2; i++)
            #pragma unroll
            for (int r2 = 0; r2 < 4; r2++) o_[d4][i][r2] = 0.f;
    #pragma unroll
    for (int i = 0; i < 2; i++)
        #pragma unroll
        for (int r2 = 0; r2 < 4; r2++) ol[i][r2] = 0.f;

    #pragma unroll 1
    for (int t = 0; t < cnt; t++) {
        if (t < nwt) {
            // ---- S^T = K Q^T ----
            ffrag st[4][2];
            bfrag kf[4];
            // ks = 0: C = zero (no accumulator pre-init needed)
            #pragma unroll
            for (int t4 = 0; t4 < 4; t4++)
                kf[t4] = *(const bfrag*)
                    &Ks[16 * t4 + col][((quad ^ (col & 7)) * 8)];
            #pragma unroll
            for (int t4 = 0; t4 < 4; t4++)
                #pragma unroll
                for (int i = 0; i < 2; i++)
                    st[t4][i] = __builtin_amdgcn_mfma_f32_16x16x32_bf16(
                        kf[t4], qf[i][0], zf, 0, 0, 0);
            // ks = 1: accumulate
            #pragma unroll
            for (int t4 = 0; t4 < 4; t4++)
                kf[t4] = *(const bfrag*)
                    &Ks[16 * t4 + col][(((4 + quad) ^ (col & 7)) * 8)];
            #pragma unroll
            for (int t4 = 0; t4 < 4; t4++)
                #pragma unroll
                for (int i = 0; i < 2; i++)
                    st[t4][i] = __builtin_amdgcn_mfma_f32_16x16x32_bf16(
                        kf[t4], qf[i][1], st[t4][i], 0, 0, 0);

            // ---- causal mask: only this wave's diagonal tile ----
            if (domask && t == nwt - 1) {
                #pragma unroll
                for (int i = 0; i < 2; i++) {
                    const int qrel = 32 * (w & 1) + 16 * i + col;
                    #pragma unroll
                    for (int t4 = 0; t4 < 4; t4++) {
                        const int key0 = 16 * t4 + 4 * quad;
                        #pragma unroll
                        for (int r2 = 0; r2 < 4; r2++)
                            if (key0 + r2 > qrel) st[t4][i][r2] = -3.0e38f;
                    }
                }
            }

            // ---- softmax numerator: p = exp2(s), no shift ----
            #pragma unroll
            for (int i = 0; i < 2; i++) {
                const int prow = 16 * i + col;
                #pragma unroll
                for (int t4 = 0; t4 < 4; t4++) {
                    float pr[4];
                    #pragma unroll
                    for (int r2 = 0; r2 < 4; r2++) pr[r2] = fexp2(st[t4][i][r2]);
                    uint2 pk;
                    pk.x = pack_bf16_trunc(pr[0], pr[1]);
                    pk.y = pack_bf16_trunc(pr[2], pr[3]);
                    const int c2 = (2 * t4 + (quad >> 1)) ^ (col & 7);
                    *(uint2*)((char*)&QP[w][prow][0] + 16 * c2 + 8 * (quad & 1)) = pk;
                }
            }
        }

        // BARRIER1: all waves done reading Ks[t]; V[t]'s staging loads
        // (issued after B2 of t-1, or in the prologue for t=kt0) drained.
        __syncthreads();

        // issue K[t+1] into Ks (safe: all QK^T reads of tile t complete)
        if (t + 1 < cnt) {
            const size_t ko = kArow + kt0off + (size_t)(t + 1) * 64 * E3;
            #pragma unroll
            for (int u = 0; u < 2; u++)
                gld16(qkvb + ko + (size_t)(8 * u) * E3, &Ks[16 * w + 8 * u][0]);
        }

        if (t < nwt) {
            // ---- O^T += V^T P^T ;  l += 1^T P^T ----
            #pragma unroll
            for (int ks = 0; ks < 2; ks++) {
                bfrag vf[4];
                #pragma unroll
                for (int d4 = 0; d4 < 4; d4++)
                    vf[d4] = *(const bfrag*)
                        &Vs[16 * d4 + col][(((4 * ks + quad) ^ (col & 7)) * 8)];
                bfrag pf[2];
                #pragma unroll
                for (int i = 0; i < 2; i++)
                    pf[i] = *(const bfrag*)
                        ((const char*)&QP[w][16 * i + col][0] +
                         16 * ((4 * ks + quad) ^ (col & 7)));
                #pragma unroll
                for (int d4 = 0; d4 < 4; d4++)
                    #pragma unroll
                    for (int i = 0; i < 2; i++)
                        o_[d4][i] = __builtin_amdgcn_mfma_f32_16x16x32_bf16(
                            vf[d4], pf[i], o_[d4][i], 0, 0, 0);
                #pragma unroll
                for (int i = 0; i < 2; i++)
                    ol[i] = __builtin_amdgcn_mfma_f32_16x16x32_bf16(
                        ones, pf[i], ol[i], 0, 0, 0);
            }
        }

        // BARRIER2: all waves done reading Vs[t]; K[t+1] staging drained.
        __syncthreads();

        // issue V[t+1] into Vs (safe: all PV reads of tile t complete)
        if (t + 1 < cnt) {
            const size_t vo = vArow + vt0off + (size_t)(t + 1) * 64;
            #pragma unroll
            for (int u = 0; u < 2; u++)
                gld16(vt + vo + (size_t)(8 * u) * S_LEN, &Vs[16 * w + 8 * u][0]);
        }
    }

    // ---- epilogue ----
    if (nc == 1) {
        // direct normalized write
        #pragma unroll
        for (int i = 0; i < 2; i++) {
            const float inv = 1.0f / ol[i][0];
            const int qg = q0 + 32 * w + 16 * i + col;
            #pragma unroll
            for (int d4 = 0; d4 < 4; d4++) {
                us4 pk;
                #pragma unroll
                for (int r2 = 0; r2 < 4; r2++) pk[r2] = f2bf(o_[d4][i][r2] * inv);
                *(us4*)&ctxb[(size_t)qg * EMB + h * HD + 16 * d4 + 4 * quad] = pk;
            }
        }
    } else {
        // partial write: bf16 O + fp32 l
        const int jj = (qi <= 21) ? (qi - 11) * 2 + ch : 22 + (qi - 22) * 3 + ch;
        const int slot = h * SLOTS_PER_HEAD + jj;
        u16* po = pO + (size_t)slot * (128 * 64);
        float* pl = pL + slot * 128;
        #pragma unroll
        for (int i = 0; i < 2; i++) {
            const int qrow = 32 * w + 16 * i + col;
            #pragma unroll
            for (int d4 = 0; d4 < 4; d4++) {
                us4 pk;
                #pragma unroll
                for (int r2 = 0; r2 < 4; r2++) pk[r2] = f2bf(o_[d4][i][r2]);
                *(us4*)&po[(size_t)qrow * 64 + 16 * d4 + 4 * quad] = pk;
            }
            if (quad == 0) pl[qrow] = ol[i][0];
        }
    }
}

// ---------------------------------------------------------------------------
// combine: out[q] = (sum_p O_p[q]) / (sum_p l_p[q]) over a group's 2-3 chunks.
// grid = 16 heads x 21 split q-blocks (qi 11..31) = 336.
// ---------------------------------------------------------------------------
__global__ __launch_bounds__(256)
void combine_kernel(const u16* __restrict__ pO, const float* __restrict__ pL,
                    u16* __restrict__ ctxb) {
    const int g = blockIdx.x;                  // 0..335
    const int h = g / 21, qq = g % 21;
    const int qi = 11 + qq;
    const int nc = (qi <= 21) ? 2 : 3;
    const int jj0 = (qi <= 21) ? (qi - 11) * 2 : 22 + (qi - 22) * 3;
    const int slot0 = h * SLOTS_PER_HEAD + jj0;

    const int t = threadIdx.x;
    const int q = t >> 1, dh = (t & 1) * 32;

    float l = 0.f;
    for (int p = 0; p < nc; p++) l += pL[(slot0 + p) * 128 + q];
    const float inv = 1.0f / l;

    u16* op = ctxb + (size_t)(qi * 128 + q) * EMB + h * HD + dh;

    #pragma unroll
    for (int j = 0; j < 4; j++) {
        float s[8] = {0.f, 0.f, 0.f, 0.f, 0.f, 0.f, 0.f, 0.f};
        for (int p = 0; p < nc; p++) {
            const us8 va = *(const us8*)
                (pO + ((size_t)(slot0 + p) * 128 + q) * 64 + dh + 8 * j);
            #pragma unroll
            for (int e = 0; e < 8; e++) s[e] += bf2f(va[e]);
        }
        us8 vo;
        #pragma unroll
        for (int e = 0; e < 8; e++) vo[e] = f2bf(s[e] * inv);
        *(us8*)(op + 8 * j) = vo;
    }
}

// ---------------------------------------------------------------------------
extern "C" void kernel_launch(void* const* d_in, const int* in_sizes, int n_in,
                              void* d_out, int out_size, void* d_ws, size_t ws_size,
                              hipStream_t stream) {
    const float* x      = (const float*)d_in[0];
    const float* wqkv_w = (const float*)d_in[2];
    const float* wqkv_b = (const float*)d_in[3];
    const float* out_w  = (const float*)d_in[4];
    const float* out_b  = (const float*)d_in[5];
    float* out = (float*)d_out;

    u16* qkvb = (u16*)d_ws;                        // [4096][3072] (V unused)
    u16* ctxb = qkvb + (size_t)S_LEN * E3;         // [4096][1024]
    u16* xb   = ctxb + (size_t)S_LEN * EMB;        // [4096][1024]
    u16* wt   = xb   + (size_t)S_LEN * EMB;        // [3072][1024]
    u16* owt  = wt   + (size_t)E3 * EMB;           // [1024][1024]
    u16* vtb  = owt  + (size_t)EMB * EMB;          // [16][64][4096]

    // flash partials alias the dead contiguous xb+wt span (14.68 MB):
    //   pO: 832 slots x 128x64 bf16 = 13.63 MB, pL: 832x128 f32 = 0.43 MB
    u16*   pO = xb;
    float* pL = (float*)(xb + (size_t)NSLOTS * 128 * 64);

    // RoPE table (1 MB) aliases ctxb: dead until flash writes it, read only
    // by gemm1's epilogue.
    float2* ropetab = (float2*)ctxb;

    dim3 blk(256);

    // fused preprocessing: cast + 2 transposes + rope table (1 launch)
    prep_kernel<<<dim3(3584), blk, 0, stream>>>(
        x, xb, wqkv_w, wt, out_w, owt, ropetab);

    // QKV projection + fused RoPE (+ q pre-scale) + fused V transpose
    gemm_bt_kernel<1, 4, 1, 3><<<dim3(S_LEN / 128, E3 / 128), blk, 0, stream>>>(
        xb, wt, wqkv_b, qkvb, vtb, ropetab, S_LEN, E3, EMB);

    flash15_kernel<<<dim3(1008), blk, 0, stream>>>(qkvb, vtb, ctxb, pO, pL);
    combine_kernel<<<dim3(336), blk, 0, stream>>>(pO, pL, ctxb);

    // output projection, 128x64 tiles -> 512 blocks (2/CU)
    gemm_bt_kernel<0, 2, 0, 2><<<dim3(S_LEN / 128, EMB / 64), blk, 0, stream>>>(
        ctxb, owt, out_b, out, nullptr, nullptr, S_LEN, EMB, EMB);
}

// Round 7
// 228.469 us; speedup vs baseline: 1.5098x; 1.0085x over previous
//
#include <hip/hip_runtime.h>
#include <hip/hip_bf16.h>
#include <math.h>

#define S_LEN 4096
#define EMB   1024
#define E3    3072
#define NH    16
#define HD    64

// flash partial-combine geometry: qi<=10 direct; qi 11..21 -> 2 chunks;
// qi 22..31 -> 3 chunks.  52 partial slots per head, 832 total.
#define SLOTS_PER_HEAD 52
#define NSLOTS         832

typedef unsigned short u16;
typedef short          bfrag __attribute__((ext_vector_type(8)));  // 8 bf16
typedef float          ffrag __attribute__((ext_vector_type(4)));  // 4 f32
typedef unsigned short us8   __attribute__((ext_vector_type(8)));
typedef unsigned short us4   __attribute__((ext_vector_type(4)));

__device__ __forceinline__ u16 f2bf(float f) {
    union { float f; unsigned u; } v; v.f = f;
    unsigned r = v.u + 0x7fffu + ((v.u >> 16) & 1u);
    return (u16)(r >> 16);
}
__device__ __forceinline__ float bf2f(u16 b) {
    union { unsigned u; float f; } v; v.u = ((unsigned)b) << 16;
    return v.f;
}
// pack two f32 -> two bf16 (truncation) in one v_perm_b32
__device__ __forceinline__ unsigned pack_bf16_trunc(float lo, float hi) {
    union { float f; unsigned u; } a, b; a.f = lo; b.f = hi;
    return __builtin_amdgcn_perm(b.u, a.u, 0x07060302u);
}
// raw v_exp_f32 (2^x).  OCML exp2f adds ~5 fixup ops for subnormals/range;
// softmax doesn't care (subnormal p -> 0 is exact enough; |s| <= ~30 here).
__device__ __forceinline__ float fexp2(float x) {
    float r;
    asm("v_exp_f32 %0, %1" : "=v"(r) : "v"(x));
    return r;
}
// async global->LDS, 16B per lane; LDS dest = uniform base + lane*16
__device__ __forceinline__ void gld16(const void* g, void* l) {
    __builtin_amdgcn_global_load_lds(
        (const __attribute__((address_space(1))) unsigned int*)g,
        (__attribute__((address_space(3))) unsigned int*)l, 16, 0, 0);
}

// ---------------------------------------------------------------------------
// prep: single kernel fusing (launch-gap reduction, bodies unchanged):
//   blocks [0,2048)      : cast x fp32 -> xb bf16 (8 elems/thread)
//   blocks [2048,2816)   : transpose+cast wqkv_w [EMB][E3] -> wt [E3][EMB]
//   blocks [2816,3072)   : transpose+cast out_w  [EMB][EMB] -> owt
//   blocks [3072,3584)   : RoPE table tab[s][j] = (cos,sin)(s*10000^(-j/32))
// ---------------------------------------------------------------------------
__device__ __forceinline__ void transpose_body(const float* __restrict__ in,
                                               u16* __restrict__ out,
                                               int R, int C, int bx, int by,
                                               u16 (*T)[72]) {
    const int r0 = bx * 64, c0 = by * 64;
    const int t = threadIdx.x;
    const int rr = t >> 2, cc = (t & 3) * 16;

    const float* ip = in + (size_t)(r0 + rr) * C + c0 + cc;
    u16 tmp[16];
    #pragma unroll
    for (int i4 = 0; i4 < 4; i4++) {
        float4 v = ((const float4*)ip)[i4];
        tmp[4*i4+0]=f2bf(v.x); tmp[4*i4+1]=f2bf(v.y);
        tmp[4*i4+2]=f2bf(v.z); tmp[4*i4+3]=f2bf(v.w);
    }
    #pragma unroll
    for (int i8 = 0; i8 < 2; i8++) {
        us8 vv;
        #pragma unroll
        for (int j = 0; j < 8; j++) vv[j] = tmp[8*i8+j];
        *(us8*)&T[rr][cc + 8*i8] = vv;
    }
    __syncthreads();

    const int oc = t >> 2, orr = (t & 3) * 16;
    u16 ot[16];
    #pragma unroll
    for (int j = 0; j < 16; j++) ot[j] = T[orr + j][oc];
    u16* op = out + (size_t)(c0 + oc) * R + r0 + orr;
    #pragma unroll
    for (int i8 = 0; i8 < 2; i8++) {
        us8 vv;
        #pragma unroll
        for (int j = 0; j < 8; j++) vv[j] = ot[8*i8+j];
        *(us8*)(op + 8*i8) = vv;
    }
}

__global__ __launch_bounds__(256)
void prep_kernel(const float* __restrict__ x, u16* __restrict__ xb,
                 const float* __restrict__ wqkv_w, u16* __restrict__ wt,
                 const float* __restrict__ out_w, u16* __restrict__ owt,
                 float2* __restrict__ tab) {
    __shared__ u16 T[64][72];
    const int b = blockIdx.x;
    if (b < 2048) {
        const size_t i = ((size_t)b * 256 + threadIdx.x) * 8;
        float4 a = *(const float4*)(x + i);
        float4 c = *(const float4*)(x + i + 4);
        us8 o;
        o[0]=f2bf(a.x); o[1]=f2bf(a.y); o[2]=f2bf(a.z); o[3]=f2bf(a.w);
        o[4]=f2bf(c.x); o[5]=f2bf(c.y); o[6]=f2bf(c.z); o[7]=f2bf(c.w);
        *(us8*)(xb + i) = o;
    } else if (b < 2816) {
        const int bb = b - 2048;
        transpose_body(wqkv_w, wt, EMB, E3, bb & 15, bb >> 4, T);
    } else if (b < 3072) {
        const int bb = b - 2816;
        transpose_body(out_w, owt, EMB, EMB, bb & 15, bb >> 4, T);
    } else {
        const int idx = (b - 3072) * 256 + threadIdx.x;   // s*32 + j
        const int s = idx >> 5, j = idx & 31;
        const float C = 13.287712379549449f / 32.0f;      // log2(10000)/32
        const float invf = exp2f(-(float)j * C);
        float sn, cs;
        sincosf((float)s * invf, &sn, &cs);
        tab[idx] = make_float2(cs, sn);
    }
}

// ---------------------------------------------------------------------------
// bf16 MFMA GEMM, double-buffered: C[M,N] = A[M,K] * Bt[N,K]^T + bias
// Tile 128 x (32*NT); 4 waves as 2m x 2n; wave does 4x NT 16x16x32 tiles.
// XCD-rect swizzle (T1): linear bid%8 = XCD on MI355X; remap so each XCD
// owns a contiguous RBXx RBY tile-rect.  Per-XCD working set then fits its
// 4 MB L2 (gemm1: 8x12 rect = 2.1 MB A + 3.1 MB B; gemm2: 8x8 = 3.2 MB)
// instead of the full 14.7 MB (thrash).  Requires gridDim = (4*RBX, 2*RBY).
// ROPE=1 (requires NT=4):
//   n0 <  2048 : fuse RoPE rotation (+0.125*log2e scale for q) -> Cv (qkvb)
//                cos/sin from precomputed table (rope)
//   n0 >= 2048 : V region -- write bias-added values TRANSPOSED to vtp[d][s]
// ---------------------------------------------------------------------------
template <int OUT_BF16, int NT, int ROPE, int MINW, int RBX, int RBY>
__global__ __launch_bounds__(256, MINW)
void gemm_bt_kernel(const u16* __restrict__ A, const u16* __restrict__ Bt,
                    const float* __restrict__ bias, void* __restrict__ Cv,
                    u16* __restrict__ vtp, const float2* __restrict__ rope,
                    int M, int N, int K) {
    constexpr int BN = 32 * NT;       // block n-span
    constexpr int WS = 16 * NT;       // wave n-span
    __shared__ u16 As[2][128][32];
    __shared__ u16 Bs[2][BN][32];

    const int tid = threadIdx.x;
    const int w = tid >> 6, L = tid & 63;
    const int col = L & 15, quad = L >> 4;
    const int wm = w & 1, wn = w >> 1;

    // XCD-rect swizzle: xcd = bid & 7 (HW round-robin), i = bid >> 3.
    // bx = (xcd&3)*RBX + i%RBX,  by = (xcd>>2)*RBY + i/RBX   (bijective).
    const int bid = blockIdx.x + gridDim.x * blockIdx.y;
    const int xcd = bid & 7, ii = bid >> 3;
    const int bx = (xcd & 3) * RBX + (ii % RBX);
    const int by = (xcd >> 2) * RBY + (ii / RBX);
    const int m0 = bx * 128, n0 = by * BN;

    ffrag acc[4][NT];
    #pragma unroll
    for (int a = 0; a < 4; a++)
        #pragma unroll
        for (int b = 0; b < NT; b++)
            #pragma unroll
            for (int r = 0; r < 4; r++) acc[a][b][r] = 0.f;

    const int srow = L >> 2;
    const int schk = L & 3;

    // prologue: stage k=0 into buf 0
    #pragma unroll
    for (int t = 0; t < 2; t++) {
        const int rg = (2 * w + t) * 16;
        gld16(A + (size_t)(m0 + rg + srow) * K + schk * 8, &As[0][rg][0]);
    }
    #pragma unroll
    for (int t = 0; t < NT / 2; t++) {
        const int rg = (w * (NT / 2) + t) * 16;
        gld16(Bt + (size_t)(n0 + rg + srow) * K + schk * 8, &Bs[0][rg][0]);
    }
    __syncthreads();

    int buf = 0;
    for (int k0 = 0; k0 < K; k0 += 32, buf ^= 1) {
        if (k0 + 32 < K) {
            #pragma unroll
            for (int t = 0; t < 2; t++) {
                const int rg = (2 * w + t) * 16;
                gld16(A + (size_t)(m0 + rg + srow) * K + k0 + 32 + schk * 8,
                      &As[buf ^ 1][rg][0]);
            }
            #pragma unroll
            for (int t = 0; t < NT / 2; t++) {
                const int rg = (w * (NT / 2) + t) * 16;
                gld16(Bt + (size_t)(n0 + rg + srow) * K + k0 + 32 + schk * 8,
                      &Bs[buf ^ 1][rg][0]);
            }
        }

        bfrag af[4], bf[NT];
        #pragma unroll
        for (int mt = 0; mt < 4; mt++)
            af[mt] = *(const bfrag*)&As[buf][64 * wm + 16 * mt + col][8 * quad];
        #pragma unroll
        for (int nt = 0; nt < NT; nt++)
            bf[nt] = *(const bfrag*)&Bs[buf][WS * wn + 16 * nt + col][8 * quad];
        #pragma unroll
        for (int mt = 0; mt < 4; mt++)
            #pragma unroll
            for (int nt = 0; nt < NT; nt++)
                acc[mt][nt] = __builtin_amdgcn_mfma_f32_16x16x32_bf16(
                    af[mt], bf[nt], acc[mt][nt], 0, 0, 0);

        __syncthreads();
    }

    float bv[NT];
    #pragma unroll
    for (int nt = 0; nt < NT; nt++) bv[nt] = bias[n0 + WS * wn + 16 * nt + col];

    if (ROPE && n0 < 2 * EMB) {
        // q (n<1024) or k (1024..2047): rotate (d, d+32) pairs, table lookup.
        const float SCq = (n0 < EMB) ? 0.125f * 1.44269504088896f : 1.0f;
        #pragma unroll
        for (int mt = 0; mt < 4; mt++) {
            #pragma unroll
            for (int r = 0; r < 4; r++) {
                const int mrow = m0 + 64 * wm + 16 * mt + 4 * quad + r;
                u16* cp = (u16*)Cv + (size_t)mrow * N + n0 + 64 * wn + col;
                #pragma unroll
                for (int pr = 0; pr < 2; pr++) {
                    const float2 t = rope[(size_t)mrow * 32 + col + 16 * pr];
                    const float cs = t.x, sn = t.y;
                    const float t1 = acc[mt][pr][r] + bv[pr];
                    const float t2 = acc[mt][pr + 2][r] + bv[pr + 2];
                    cp[16 * pr]      = f2bf((t1 * cs - t2 * sn) * SCq);
                    cp[16 * pr + 32] = f2bf((t2 * cs + t1 * sn) * SCq);
                }
            }
        }
    } else if (ROPE) {
        // V region: write transposed to vtp[d][s], d = n - 2048.
        #pragma unroll
        for (int nt = 0; nt < NT; nt++) {
            const int dg = n0 - 2 * EMB + WS * wn + 16 * nt + col;
            #pragma unroll
            for (int mt = 0; mt < 4; mt++) {
                const int s0 = m0 + 64 * wm + 16 * mt + 4 * quad;
                us4 pk;
                #pragma unroll
                for (int r = 0; r < 4; r++) pk[r] = f2bf(acc[mt][nt][r] + bv[nt]);
                *(us4*)&vtp[(size_t)dg * S_LEN + s0] = pk;
            }
        }
    } else {
        #pragma unroll
        for (int mt = 0; mt < 4; mt++) {
            #pragma unroll
            for (int r = 0; r < 4; r++) {
                const int m = m0 + 64 * wm + 16 * mt + 4 * quad + r;
                #pragma unroll
                for (int nt = 0; nt < NT; nt++) {
                    const int n = n0 + WS * wn + 16 * nt + col;
                    const float val = acc[mt][nt][r] + bv[nt];
                    if (OUT_BF16) ((u16*)Cv)[(size_t)m * N + n] = f2bf(val);
                    else          ((float*)Cv)[(size_t)m * N + n] = val;
                }
            }
        }
    }
}

// ---------------------------------------------------------------------------
// flash15: fexp2 + zero-C QK body; 2-barrier single-buffered K/V (32 KB LDS,
// 4 blocks/CU, launch_bounds(256,4) -- reg cap 128, no spill; round-3's
// catastrophe was the MINW=5 cap of 102 total regs incl. AGPRs).
// Per tile:  QK^T(Ks) -> softmax -> B1 -> issue K[t+1] -> PV(Vs) -> B2
//            -> issue V[t+1]
// Schedule: qi<=10 direct; qi 11..21 2 chunks; qi 22..31 3 chunks;
// 1008 blocks, longest-first per XCD lane, id&7 = XCD, 2 heads/XCD.
// ---------------------------------------------------------------------------
__global__ __launch_bounds__(256, 4)
void flash15_kernel(const u16* __restrict__ qkvb, const u16* __restrict__ vt,
                    u16* __restrict__ ctxb, u16* __restrict__ pO,
                    float* __restrict__ pL) {
    __shared__ u16 QP[4][32][64];     // per-wave: Q rows, then P overlay
    __shared__ u16 Ks[64][64];
    __shared__ u16 Vs[64][64];

    const int id = blockIdx.x;                    // 0..1007
    const int x  = id & 7;                        // XCD
    const int tt = id >> 3;                       // 0..125
    const int h  = x + 8 * (tt & 1);              // 2 heads per XCD, interleaved
    const int o  = tt >> 1;                       // 0..62 order index, long-first

    int qi, ch, nc;
    if (o < 30)      { qi = 31 - o / 3;        ch = o % 3;        nc = 3; }
    else if (o < 33) { qi = 10 - (o - 30);     ch = 0;            nc = 1; }
    else if (o < 55) { const int oo = o - 33;  qi = 21 - oo / 2;  ch = oo & 1; nc = 2; }
    else             { qi = 7 - (o - 55);      ch = 0;            nc = 1; }

    const int total = 2 * qi + 2;
    const int Lc    = (total + nc - 1) / nc;
    const int kt0   = ch * Lc;
    const int cnt   = min(Lc, total - kt0);
    const bool lastch = (kt0 + cnt == total);     // chunk holding the diagonal
    const int q0 = qi * 128;

    const int tid = threadIdx.x;
    const int w = tid >> 6, L = tid & 63;
    const int col = L & 15, quad = L >> 4;
    const int lr = L >> 3, lp = L & 7;
    const int lc = lp ^ lr;                       // swizzled chunk for staging

    const bool domask = lastch;
    const int nwt = cnt - ((domask && w < 2) ? 1 : 0);

    const size_t kArow = (size_t)(16 * w + lr) * E3 + EMB + h * HD + lc * 8;
    const size_t vArow = ((size_t)h * HD + 16 * w + lr) * S_LEN + lc * 8;
    const size_t kt0off  = (size_t)kt0 * 64 * E3;
    const size_t vt0off  = (size_t)kt0 * 64;

    // ---- stage Q (own wave's 32 rows) + K/V tile kt0 ----
    #pragma unroll
    for (int u = 0; u < 4; u++)
        gld16(qkvb + (size_t)(q0 + 32 * w + 8 * u + lr) * E3 + h * HD + lc * 8,
              &QP[w][8 * u][0]);
    #pragma unroll
    for (int u = 0; u < 2; u++) {
        gld16(qkvb + kArow + kt0off + (size_t)(8 * u) * E3,
              &Ks[16 * w + 8 * u][0]);
        gld16(vt + vArow + vt0off + (size_t)(8 * u) * S_LEN,
              &Vs[16 * w + 8 * u][0]);
    }
    __syncthreads();

    bfrag qf[2][2];
    #pragma unroll
    for (int i = 0; i < 2; i++)
        #pragma unroll
        for (int ks = 0; ks < 2; ks++)
            qf[i][ks] = *(const bfrag*)
                ((const char*)&QP[w][16 * i + col][0] +
                 16 * ((4 * ks + quad) ^ (col & 7)));

    bfrag ones;
    #pragma unroll
    for (int i = 0; i < 8; i++) ones[i] = (short)0x3F80;
    const ffrag zf = {0.f, 0.f, 0.f, 0.f};

    ffrag o_[4][2], ol[2];
    #pragma unroll
    for (int d4 = 0; d4 < 4; d4++)
        #pragma unroll
        for (int i = 0; i < 2; i++)
            #pragma unroll
            for (int r2 = 0; r2 < 4; r2++) o_[d4][i][r2] = 0.f;
    #pragma unroll
    for (int i = 0; i < 2; i++)
        #pragma unroll
        for (int r2 = 0; r2 < 4; r2++) ol[i][r2] = 0.f;

    #pragma unroll 1
    for (int t = 0; t < cnt; t++) {
        if (t < nwt) {
            // ---- S^T = K Q^T ----
            ffrag st[4][2];
            bfrag kf[4];
            // ks = 0: C = zero (no accumulator pre-init needed)
            #pragma unroll
            for (int t4 = 0; t4 < 4; t4++)
                kf[t4] = *(const bfrag*)
                    &Ks[16 * t4 + col][((quad ^ (col & 7)) * 8)];
            #pragma unroll
            for (int t4 = 0; t4 < 4; t4++)
                #pragma unroll
                for (int i = 0; i < 2; i++)
                    st[t4][i] = __builtin_amdgcn_mfma_f32_16x16x32_bf16(
                        kf[t4], qf[i][0], zf, 0, 0, 0);
            // ks = 1: accumulate
            #pragma unroll
            for (int t4 = 0; t4 < 4; t4++)
                kf[t4] = *(const bfrag*)
                    &Ks[16 * t4 + col][(((4 + quad) ^ (col & 7)) * 8)];
            #pragma unroll
            for (int t4 = 0; t4 < 4; t4++)
                #pragma unroll
                for (int i = 0; i < 2; i++)
                    st[t4][i] = __builtin_amdgcn_mfma_f32_16x16x32_bf16(
                        kf[t4], qf[i][1], st[t4][i], 0, 0, 0);

            // ---- causal mask: only this wave's diagonal tile ----
            if (domask && t == nwt - 1) {
                #pragma unroll
                for (int i = 0; i < 2; i++) {
                    const int qrel = 32 * (w & 1) + 16 * i + col;
                    #pragma unroll
                    for (int t4 = 0; t4 < 4; t4++) {
                        const int key0 = 16 * t4 + 4 * quad;
                        #pragma unroll
                        for (int r2 = 0; r2 < 4; r2++)
                            if (key0 + r2 > qrel) st[t4][i][r2] = -3.0e38f;
                    }
                }
            }

            // ---- softmax numerator: p = exp2(s), no shift ----
            #pragma unroll
            for (int i = 0; i < 2; i++) {
                const int prow = 16 * i + col;
                #pragma unroll
                for (int t4 = 0; t4 < 4; t4++) {
                    float pr[4];
                    #pragma unroll
                    for (int r2 = 0; r2 < 4; r2++) pr[r2] = fexp2(st[t4][i][r2]);
                    uint2 pk;
                    pk.x = pack_bf16_trunc(pr[0], pr[1]);
                    pk.y = pack_bf16_trunc(pr[2], pr[3]);
                    const int c2 = (2 * t4 + (quad >> 1)) ^ (col & 7);
                    *(uint2*)((char*)&QP[w][prow][0] + 16 * c2 + 8 * (quad & 1)) = pk;
                }
            }
        }

        // BARRIER1: all waves done reading Ks[t]; V[t]'s staging loads
        // (issued after B2 of t-1, or in the prologue for t=kt0) drained.
        __syncthreads();

        // issue K[t+1] into Ks (safe: all QK^T reads of tile t complete)
        if (t + 1 < cnt) {
            const size_t ko = kArow + kt0off + (size_t)(t + 1) * 64 * E3;
            #pragma unroll
            for (int u = 0; u < 2; u++)
                gld16(qkvb + ko + (size_t)(8 * u) * E3, &Ks[16 * w + 8 * u][0]);
        }

        if (t < nwt) {
            // ---- O^T += V^T P^T ;  l += 1^T P^T ----
            #pragma unroll
            for (int ks = 0; ks < 2; ks++) {
                bfrag vf[4];
                #pragma unroll
                for (int d4 = 0; d4 < 4; d4++)
                    vf[d4] = *(const bfrag*)
                        &Vs[16 * d4 + col][(((4 * ks + quad) ^ (col & 7)) * 8)];
                bfrag pf[2];
                #pragma unroll
                for (int i = 0; i < 2; i++)
                    pf[i] = *(const bfrag*)
                        ((const char*)&QP[w][16 * i + col][0] +
                         16 * ((4 * ks + quad) ^ (col & 7)));
                #pragma unroll
                for (int d4 = 0; d4 < 4; d4++)
                    #pragma unroll
                    for (int i = 0; i < 2; i++)
                        o_[d4][i] = __builtin_amdgcn_mfma_f32_16x16x32_bf16(
                            vf[d4], pf[i], o_[d4][i], 0, 0, 0);
                #pragma unroll
                for (int i = 0; i < 2; i++)
                    ol[i] = __builtin_amdgcn_mfma_f32_16x16x32_bf16(
                        ones, pf[i], ol[i], 0, 0, 0);
            }
        }

        // BARRIER2: all waves done reading Vs[t]; K[t+1] staging drained.
        __syncthreads();

        // issue V[t+1] into Vs (safe: all PV reads of tile t complete)
        if (t + 1 < cnt) {
            const size_t vo = vArow + vt0off + (size_t)(t + 1) * 64;
            #pragma unroll
            for (int u = 0; u < 2; u++)
                gld16(vt + vo + (size_t)(8 * u) * S_LEN, &Vs[16 * w + 8 * u][0]);
        }
    }

    // ---- epilogue ----
    if (nc == 1) {
        // direct normalized write
        #pragma unroll
        for (int i = 0; i < 2; i++) {
            const float inv = 1.0f / ol[i][0];
            const int qg = q0 + 32 * w + 16 * i + col;
            #pragma unroll
            for (int d4 = 0; d4 < 4; d4++) {
                us4 pk;
                #pragma unroll
                for (int r2 = 0; r2 < 4; r2++) pk[r2] = f2bf(o_[d4][i][r2] * inv);
                *(us4*)&ctxb[(size_t)qg * EMB + h * HD + 16 * d4 + 4 * quad] = pk;
            }
        }
    } else {
        // partial write: bf16 O + fp32 l
        const int jj = (qi <= 21) ? (qi - 11) * 2 + ch : 22 + (qi - 22) * 3 + ch;
        const int slot = h * SLOTS_PER_HEAD + jj;
        u16* po = pO + (size_t)slot * (128 * 64);
        float* pl = pL + slot * 128;
        #pragma unroll
        for (int i = 0; i < 2; i++) {
            const int qrow = 32 * w + 16 * i + col;
            #pragma unroll
            for (int d4 = 0; d4 < 4; d4++) {
                us4 pk;
                #pragma unroll
                for (int r2 = 0; r2 < 4; r2++) pk[r2] = f2bf(o_[d4][i][r2]);
                *(us4*)&po[(size_t)qrow * 64 + 16 * d4 + 4 * quad] = pk;
            }
            if (quad == 0) pl[qrow] = ol[i][0];
        }
    }
}

// ---------------------------------------------------------------------------
// combine: out[q] = (sum_p O_p[q]) / (sum_p l_p[q]) over a group's 2-3 chunks.
// grid = 16 heads x 21 split q-blocks (qi 11..31) = 336.
// ---------------------------------------------------------------------------
__global__ __launch_bounds__(256)
void combine_kernel(const u16* __restrict__ pO, const float* __restrict__ pL,
                    u16* __restrict__ ctxb) {
    const int g = blockIdx.x;                  // 0..335
    const int h = g / 21, qq = g % 21;
    const int qi = 11 + qq;
    const int nc = (qi <= 21) ? 2 : 3;
    const int jj0 = (qi <= 21) ? (qi - 11) * 2 : 22 + (qi - 22) * 3;
    const int slot0 = h * SLOTS_PER_HEAD + jj0;

    const int t = threadIdx.x;
    const int q = t >> 1, dh = (t & 1) * 32;

    float l = 0.f;
    for (int p = 0; p < nc; p++) l += pL[(slot0 + p) * 128 + q];
    const float inv = 1.0f / l;

    u16* op = ctxb + (size_t)(qi * 128 + q) * EMB + h * HD + dh;

    #pragma unroll
    for (int j = 0; j < 4; j++) {
        float s[8] = {0.f, 0.f, 0.f, 0.f, 0.f, 0.f, 0.f, 0.f};
        for (int p = 0; p < nc; p++) {
            const us8 va = *(const us8*)
                (pO + ((size_t)(slot0 + p) * 128 + q) * 64 + dh + 8 * j);
            #pragma unroll
            for (int e = 0; e < 8; e++) s[e] += bf2f(va[e]);
        }
        us8 vo;
        #pragma unroll
        for (int e = 0; e < 8; e++) vo[e] = f2bf(s[e] * inv);
        *(us8*)(op + 8 * j) = vo;
    }
}

// ---------------------------------------------------------------------------
extern "C" void kernel_launch(void* const* d_in, const int* in_sizes, int n_in,
                              void* d_out, int out_size, void* d_ws, size_t ws_size,
                              hipStream_t stream) {
    const float* x      = (const float*)d_in[0];
    const float* wqkv_w = (const float*)d_in[2];
    const float* wqkv_b = (const float*)d_in[3];
    const float* out_w  = (const float*)d_in[4];
    const float* out_b  = (const float*)d_in[5];
    float* out = (float*)d_out;

    u16* qkvb = (u16*)d_ws;                        // [4096][3072] (V unused)
    u16* ctxb = qkvb + (size_t)S_LEN * E3;         // [4096][1024]
    u16* xb   = ctxb + (size_t)S_LEN * EMB;        // [4096][1024]
    u16* wt   = xb   + (size_t)S_LEN * EMB;        // [3072][1024]
    u16* owt  = wt   + (size_t)E3 * EMB;           // [1024][1024]
    u16* vtb  = owt  + (size_t)EMB * EMB;          // [16][64][4096]

    // flash partials alias the dead contiguous xb+wt span (14.68 MB):
    //   pO: 832 slots x 128x64 bf16 = 13.63 MB, pL: 832x128 f32 = 0.43 MB
    u16*   pO = xb;
    float* pL = (float*)(xb + (size_t)NSLOTS * 128 * 64);

    // RoPE table (1 MB) aliases ctxb: dead until flash writes it, read only
    // by gemm1's epilogue.
    float2* ropetab = (float2*)ctxb;

    dim3 blk(256);

    // fused preprocessing: cast + 2 transposes + rope table (1 launch)
    prep_kernel<<<dim3(3584), blk, 0, stream>>>(
        x, xb, wqkv_w, wt, out_w, owt, ropetab);

    // QKV projection + fused RoPE (+ q pre-scale) + fused V transpose
    // grid 32x24; XCD rect 8x12
    gemm_bt_kernel<1, 4, 1, 3, 8, 12>
        <<<dim3(S_LEN / 128, E3 / 128), blk, 0, stream>>>(
        xb, wt, wqkv_b, qkvb, vtb, ropetab, S_LEN, E3, EMB);

    flash15_kernel<<<dim3(1008), blk, 0, stream>>>(qkvb, vtb, ctxb, pO, pL);
    combine_kernel<<<dim3(336), blk, 0, stream>>>(pO, pL, ctxb);

    // output projection, grid 32x16; XCD rect 8x8
    gemm_bt_kernel<0, 2, 0, 2, 8, 8>
        <<<dim3(S_LEN / 128, EMB / 64), blk, 0, stream>>>(
        ctxb, owt, out_b, out, nullptr, nullptr, S_LEN, EMB, EMB);
}

// Round 8
// 225.595 us; speedup vs baseline: 1.5290x; 1.0127x over previous
//
#include <hip/hip_runtime.h>
#include <hip/hip_bf16.h>
#include <math.h>

#define S_LEN 4096
#define EMB   1024
#define E3    3072
#define NH    16
#define HD    64

// flash partial-combine geometry: qi<=10 direct; qi 11..21 -> 2 chunks;
// qi 22..31 -> 3 chunks.  52 partial slots per head, 832 total.
#define SLOTS_PER_HEAD 52
#define NSLOTS         832

typedef unsigned short u16;
typedef short          bfrag __attribute__((ext_vector_type(8)));  // 8 bf16
typedef float          ffrag __attribute__((ext_vector_type(4)));  // 4 f32
typedef unsigned short us8   __attribute__((ext_vector_type(8)));
typedef unsigned short us4   __attribute__((ext_vector_type(4)));

__device__ __forceinline__ u16 f2bf(float f) {
    union { float f; unsigned u; } v; v.f = f;
    unsigned r = v.u + 0x7fffu + ((v.u >> 16) & 1u);
    return (u16)(r >> 16);
}
__device__ __forceinline__ float bf2f(u16 b) {
    union { unsigned u; float f; } v; v.u = ((unsigned)b) << 16;
    return v.f;
}
// pack two f32 -> two bf16 (truncation) in one v_perm_b32
__device__ __forceinline__ unsigned pack_bf16_trunc(float lo, float hi) {
    union { float f; unsigned u; } a, b; a.f = lo; b.f = hi;
    return __builtin_amdgcn_perm(b.u, a.u, 0x07060302u);
}
// raw v_exp_f32 (2^x).  OCML exp2f adds ~5 fixup ops for subnormals/range;
// softmax doesn't care (subnormal p -> 0 is exact enough; |s| <= ~30 here).
__device__ __forceinline__ float fexp2(float x) {
    float r;
    asm("v_exp_f32 %0, %1" : "=v"(r) : "v"(x));
    return r;
}
// register-pair half swaps (gfx950): 2x2 transpose of (reg, lane-group).
//   permlane32: a' = {a.lo32, b.lo32}, b' = {a.hi32, b.hi32}
//   permlane16: within each 32-half, a's odd 16-group <-> b's even 16-group
__device__ __forceinline__ void pl32swap(unsigned &a, unsigned &b) {
    asm volatile("v_permlane32_swap_b32 %0, %1" : "+v"(a), "+v"(b));
}
__device__ __forceinline__ void pl16swap(unsigned &a, unsigned &b) {
    asm volatile("v_permlane16_swap_b32 %0, %1" : "+v"(a), "+v"(b));
}
// async global->LDS, 16B per lane; LDS dest = uniform base + lane*16
__device__ __forceinline__ void gld16(const void* g, void* l) {
    __builtin_amdgcn_global_load_lds(
        (const __attribute__((address_space(1))) unsigned int*)g,
        (__attribute__((address_space(3))) unsigned int*)l, 16, 0, 0);
}

// ---------------------------------------------------------------------------
// prep: single kernel fusing (launch-gap reduction, bodies unchanged):
//   blocks [0,2048)      : cast x fp32 -> xb bf16 (8 elems/thread)
//   blocks [2048,2816)   : transpose+cast wqkv_w [EMB][E3] -> wt [E3][EMB]
//   blocks [2816,3072)   : transpose+cast out_w  [EMB][EMB] -> owt
//   blocks [3072,3584)   : RoPE table tab[s][j] = (cos,sin)(s*10000^(-j/32))
// ---------------------------------------------------------------------------
__device__ __forceinline__ void transpose_body(const float* __restrict__ in,
                                               u16* __restrict__ out,
                                               int R, int C, int bx, int by,
                                               u16 (*T)[72]) {
    const int r0 = bx * 64, c0 = by * 64;
    const int t = threadIdx.x;
    const int rr = t >> 2, cc = (t & 3) * 16;

    const float* ip = in + (size_t)(r0 + rr) * C + c0 + cc;
    u16 tmp[16];
    #pragma unroll
    for (int i4 = 0; i4 < 4; i4++) {
        float4 v = ((const float4*)ip)[i4];
        tmp[4*i4+0]=f2bf(v.x); tmp[4*i4+1]=f2bf(v.y);
        tmp[4*i4+2]=f2bf(v.z); tmp[4*i4+3]=f2bf(v.w);
    }
    #pragma unroll
    for (int i8 = 0; i8 < 2; i8++) {
        us8 vv;
        #pragma unroll
        for (int j = 0; j < 8; j++) vv[j] = tmp[8*i8+j];
        *(us8*)&T[rr][cc + 8*i8] = vv;
    }
    __syncthreads();

    const int oc = t >> 2, orr = (t & 3) * 16;
    u16 ot[16];
    #pragma unroll
    for (int j = 0; j < 16; j++) ot[j] = T[orr + j][oc];
    u16* op = out + (size_t)(c0 + oc) * R + r0 + orr;
    #pragma unroll
    for (int i8 = 0; i8 < 2; i8++) {
        us8 vv;
        #pragma unroll
        for (int j = 0; j < 8; j++) vv[j] = ot[8*i8+j];
        *(us8*)(op + 8*i8) = vv;
    }
}

__global__ __launch_bounds__(256)
void prep_kernel(const float* __restrict__ x, u16* __restrict__ xb,
                 const float* __restrict__ wqkv_w, u16* __restrict__ wt,
                 const float* __restrict__ out_w, u16* __restrict__ owt,
                 float2* __restrict__ tab) {
    __shared__ u16 T[64][72];
    const int b = blockIdx.x;
    if (b < 2048) {
        const size_t i = ((size_t)b * 256 + threadIdx.x) * 8;
        float4 a = *(const float4*)(x + i);
        float4 c = *(const float4*)(x + i + 4);
        us8 o;
        o[0]=f2bf(a.x); o[1]=f2bf(a.y); o[2]=f2bf(a.z); o[3]=f2bf(a.w);
        o[4]=f2bf(c.x); o[5]=f2bf(c.y); o[6]=f2bf(c.z); o[7]=f2bf(c.w);
        *(us8*)(xb + i) = o;
    } else if (b < 2816) {
        const int bb = b - 2048;
        transpose_body(wqkv_w, wt, EMB, E3, bb & 15, bb >> 4, T);
    } else if (b < 3072) {
        const int bb = b - 2816;
        transpose_body(out_w, owt, EMB, EMB, bb & 15, bb >> 4, T);
    } else {
        const int idx = (b - 3072) * 256 + threadIdx.x;   // s*32 + j
        const int s = idx >> 5, j = idx & 31;
        const float C = 13.287712379549449f / 32.0f;      // log2(10000)/32
        const float invf = exp2f(-(float)j * C);
        float sn, cs;
        sincosf((float)s * invf, &sn, &cs);
        tab[idx] = make_float2(cs, sn);
    }
}

// ---------------------------------------------------------------------------
// bf16 MFMA GEMM, double-buffered: C[M,N] = A[M,K] * Bt[N,K]^T + bias
// Tile 128 x (32*NT); 4 waves as 2m x 2n; wave does 4x NT 16x16x32 tiles.
// XCD-rect swizzle (T1): each XCD owns a contiguous RBX x RBY tile-rect so
// its working set fits the 4 MB per-XCD L2.  (+~2 us measured, round 7.)
// ROPE=1 (requires NT=4):
//   n0 <  2048 : fuse RoPE rotation (+0.125*log2e scale for q) -> Cv (qkvb)
//                cos/sin from precomputed table (rope)
//   n0 >= 2048 : V region -- write bias-added values TRANSPOSED to vtp[d][s]
// ---------------------------------------------------------------------------
template <int OUT_BF16, int NT, int ROPE, int MINW, int RBX, int RBY>
__global__ __launch_bounds__(256, MINW)
void gemm_bt_kernel(const u16* __restrict__ A, const u16* __restrict__ Bt,
                    const float* __restrict__ bias, void* __restrict__ Cv,
                    u16* __restrict__ vtp, const float2* __restrict__ rope,
                    int M, int N, int K) {
    constexpr int BN = 32 * NT;       // block n-span
    constexpr int WS = 16 * NT;       // wave n-span
    __shared__ u16 As[2][128][32];
    __shared__ u16 Bs[2][BN][32];

    const int tid = threadIdx.x;
    const int w = tid >> 6, L = tid & 63;
    const int col = L & 15, quad = L >> 4;
    const int wm = w & 1, wn = w >> 1;

    // XCD-rect swizzle: xcd = bid & 7 (HW round-robin), i = bid >> 3.
    const int bid = blockIdx.x + gridDim.x * blockIdx.y;
    const int xcd = bid & 7, ii = bid >> 3;
    const int bx = (xcd & 3) * RBX + (ii % RBX);
    const int by = (xcd >> 2) * RBY + (ii / RBX);
    const int m0 = bx * 128, n0 = by * BN;

    ffrag acc[4][NT];
    #pragma unroll
    for (int a = 0; a < 4; a++)
        #pragma unroll
        for (int b = 0; b < NT; b++)
            #pragma unroll
            for (int r = 0; r < 4; r++) acc[a][b][r] = 0.f;

    const int srow = L >> 2;
    const int schk = L & 3;

    // prologue: stage k=0 into buf 0
    #pragma unroll
    for (int t = 0; t < 2; t++) {
        const int rg = (2 * w + t) * 16;
        gld16(A + (size_t)(m0 + rg + srow) * K + schk * 8, &As[0][rg][0]);
    }
    #pragma unroll
    for (int t = 0; t < NT / 2; t++) {
        const int rg = (w * (NT / 2) + t) * 16;
        gld16(Bt + (size_t)(n0 + rg + srow) * K + schk * 8, &Bs[0][rg][0]);
    }
    __syncthreads();

    int buf = 0;
    for (int k0 = 0; k0 < K; k0 += 32, buf ^= 1) {
        if (k0 + 32 < K) {
            #pragma unroll
            for (int t = 0; t < 2; t++) {
                const int rg = (2 * w + t) * 16;
                gld16(A + (size_t)(m0 + rg + srow) * K + k0 + 32 + schk * 8,
                      &As[buf ^ 1][rg][0]);
            }
            #pragma unroll
            for (int t = 0; t < NT / 2; t++) {
                const int rg = (w * (NT / 2) + t) * 16;
                gld16(Bt + (size_t)(n0 + rg + srow) * K + k0 + 32 + schk * 8,
                      &Bs[buf ^ 1][rg][0]);
            }
        }

        bfrag af[4], bf[NT];
        #pragma unroll
        for (int mt = 0; mt < 4; mt++)
            af[mt] = *(const bfrag*)&As[buf][64 * wm + 16 * mt + col][8 * quad];
        #pragma unroll
        for (int nt = 0; nt < NT; nt++)
            bf[nt] = *(const bfrag*)&Bs[buf][WS * wn + 16 * nt + col][8 * quad];
        #pragma unroll
        for (int mt = 0; mt < 4; mt++)
            #pragma unroll
            for (int nt = 0; nt < NT; nt++)
                acc[mt][nt] = __builtin_amdgcn_mfma_f32_16x16x32_bf16(
                    af[mt], bf[nt], acc[mt][nt], 0, 0, 0);

        __syncthreads();
    }

    float bv[NT];
    #pragma unroll
    for (int nt = 0; nt < NT; nt++) bv[nt] = bias[n0 + WS * wn + 16 * nt + col];

    if (ROPE && n0 < 2 * EMB) {
        // q (n<1024) or k (1024..2047): rotate (d, d+32) pairs, table lookup.
        const float SCq = (n0 < EMB) ? 0.125f * 1.44269504088896f : 1.0f;
        #pragma unroll
        for (int mt = 0; mt < 4; mt++) {
            #pragma unroll
            for (int r = 0; r < 4; r++) {
                const int mrow = m0 + 64 * wm + 16 * mt + 4 * quad + r;
                u16* cp = (u16*)Cv + (size_t)mrow * N + n0 + 64 * wn + col;
                #pragma unroll
                for (int pr = 0; pr < 2; pr++) {
                    const float2 t = rope[(size_t)mrow * 32 + col + 16 * pr];
                    const float cs = t.x, sn = t.y;
                    const float t1 = acc[mt][pr][r] + bv[pr];
                    const float t2 = acc[mt][pr + 2][r] + bv[pr + 2];
                    cp[16 * pr]      = f2bf((t1 * cs - t2 * sn) * SCq);
                    cp[16 * pr + 32] = f2bf((t2 * cs + t1 * sn) * SCq);
                }
            }
        }
    } else if (ROPE) {
        // V region: write transposed to vtp[d][s], d = n - 2048.
        #pragma unroll
        for (int nt = 0; nt < NT; nt++) {
            const int dg = n0 - 2 * EMB + WS * wn + 16 * nt + col;
            #pragma unroll
            for (int mt = 0; mt < 4; mt++) {
                const int s0 = m0 + 64 * wm + 16 * mt + 4 * quad;
                us4 pk;
                #pragma unroll
                for (int r = 0; r < 4; r++) pk[r] = f2bf(acc[mt][nt][r] + bv[nt]);
                *(us4*)&vtp[(size_t)dg * S_LEN + s0] = pk;
            }
        }
    } else {
        #pragma unroll
        for (int mt = 0; mt < 4; mt++) {
            #pragma unroll
            for (int r = 0; r < 4; r++) {
                const int m = m0 + 64 * wm + 16 * mt + 4 * quad + r;
                #pragma unroll
                for (int nt = 0; nt < NT; nt++) {
                    const int n = n0 + WS * wn + 16 * nt + col;
                    const float val = acc[mt][nt][r] + bv[nt];
                    if (OUT_BF16) ((u16*)Cv)[(size_t)m * N + n] = f2bf(val);
                    else          ((float*)Cv)[(size_t)m * N + n] = val;
                }
            }
        }
    }
}

// ---------------------------------------------------------------------------
// flash16: flash15 + P redistribution moved from LDS to permlane swaps.
// LDS-pipe arithmetic (round-7): ~28 LDS ops/wave-tile x ~12cyc ~= 72% of
// wall -> LDS-bound.  The P round-trip (8 ds_write_b64 + 4 ds_read_b128,
// ~1/3 of LDS traffic) is INTRA-WAVE cross-lane movement: replaced by a
// bit-transpose network of 4x v_permlane32_swap + 4x v_permlane16_swap per
// half-tile (reg-bit <-> lane-bit5, then reg-bit <-> lane-bit4), verified by
// element trace.  P never touches LDS; QP is Q-staging only.
// Structure otherwise = flash15: 2-barrier single-buffered K/V, 32 KB LDS,
// 4 blocks/CU, launch_bounds(256,4) (reg cap 128; body ~80 regs, no spill).
// ---------------------------------------------------------------------------
__global__ __launch_bounds__(256, 4)
void flash16_kernel(const u16* __restrict__ qkvb, const u16* __restrict__ vt,
                    u16* __restrict__ ctxb, u16* __restrict__ pO,
                    float* __restrict__ pL) {
    __shared__ u16 QP[4][32][64];     // Q staging only (dead after prologue)
    __shared__ u16 Ks[64][64];
    __shared__ u16 Vs[64][64];

    const int id = blockIdx.x;                    // 0..1007
    const int x  = id & 7;                        // XCD
    const int tt = id >> 3;                       // 0..125
    const int h  = x + 8 * (tt & 1);              // 2 heads per XCD, interleaved
    const int o  = tt >> 1;                       // 0..62 order index, long-first

    int qi, ch, nc;
    if (o < 30)      { qi = 31 - o / 3;        ch = o % 3;        nc = 3; }
    else if (o < 33) { qi = 10 - (o - 30);     ch = 0;            nc = 1; }
    else if (o < 55) { const int oo = o - 33;  qi = 21 - oo / 2;  ch = oo & 1; nc = 2; }
    else             { qi = 7 - (o - 55);      ch = 0;            nc = 1; }

    const int total = 2 * qi + 2;
    const int Lc    = (total + nc - 1) / nc;
    const int kt0   = ch * Lc;
    const int cnt   = min(Lc, total - kt0);
    const bool lastch = (kt0 + cnt == total);     // chunk holding the diagonal
    const int q0 = qi * 128;

    const int tid = threadIdx.x;
    const int w = tid >> 6, L = tid & 63;
    const int col = L & 15, quad = L >> 4;
    const int lr = L >> 3, lp = L & 7;
    const int lc = lp ^ lr;                       // swizzled chunk for staging

    const bool domask = lastch;
    const int nwt = cnt - ((domask && w < 2) ? 1 : 0);

    const size_t kArow = (size_t)(16 * w + lr) * E3 + EMB + h * HD + lc * 8;
    const size_t vArow = ((size_t)h * HD + 16 * w + lr) * S_LEN + lc * 8;
    const size_t kt0off  = (size_t)kt0 * 64 * E3;
    const size_t vt0off  = (size_t)kt0 * 64;

    // ---- stage Q (own wave's 32 rows) + K/V tile kt0 ----
    #pragma unroll
    for (int u = 0; u < 4; u++)
        gld16(qkvb + (size_t)(q0 + 32 * w + 8 * u + lr) * E3 + h * HD + lc * 8,
              &QP[w][8 * u][0]);
    #pragma unroll
    for (int u = 0; u < 2; u++) {
        gld16(qkvb + kArow + kt0off + (size_t)(8 * u) * E3,
              &Ks[16 * w + 8 * u][0]);
        gld16(vt + vArow + vt0off + (size_t)(8 * u) * S_LEN,
              &Vs[16 * w + 8 * u][0]);
    }
    __syncthreads();

    bfrag qf[2][2];
    #pragma unroll
    for (int i = 0; i < 2; i++)
        #pragma unroll
        for (int ks = 0; ks < 2; ks++)
            qf[i][ks] = *(const bfrag*)
                ((const char*)&QP[w][16 * i + col][0] +
                 16 * ((4 * ks + quad) ^ (col & 7)));

    bfrag ones;
    #pragma unroll
    for (int i = 0; i < 8; i++) ones[i] = (short)0x3F80;
    const ffrag zf = {0.f, 0.f, 0.f, 0.f};

    ffrag o_[4][2], ol[2];
    #pragma unroll
    for (int d4 = 0; d4 < 4; d4++)
        #pragma unroll
        for (int i = 0; i < 2; i++)
            #pragma unroll
            for (int r2 = 0; r2 < 4; r2++) o_[d4][i][r2] = 0.f;
    #pragma unroll
    for (int i = 0; i < 2; i++)
        #pragma unroll
        for (int r2 = 0; r2 < 4; r2++) ol[i][r2] = 0.f;

    #pragma unroll 1
    for (int t = 0; t < cnt; t++) {
        bfrag pfr[2][2];                 // P fragments, built in-register
        if (t < nwt) {
            // ---- S^T = K Q^T ----
            ffrag st[4][2];
            bfrag kf[4];
            // ks = 0: C = zero (no accumulator pre-init needed)
            #pragma unroll
            for (int t4 = 0; t4 < 4; t4++)
                kf[t4] = *(const bfrag*)
                    &Ks[16 * t4 + col][((quad ^ (col & 7)) * 8)];
            #pragma unroll
            for (int t4 = 0; t4 < 4; t4++)
                #pragma unroll
                for (int i = 0; i < 2; i++)
                    st[t4][i] = __builtin_amdgcn_mfma_f32_16x16x32_bf16(
                        kf[t4], qf[i][0], zf, 0, 0, 0);
            // ks = 1: accumulate
            #pragma unroll
            for (int t4 = 0; t4 < 4; t4++)
                kf[t4] = *(const bfrag*)
                    &Ks[16 * t4 + col][(((4 + quad) ^ (col & 7)) * 8)];
            #pragma unroll
            for (int t4 = 0; t4 < 4; t4++)
                #pragma unroll
                for (int i = 0; i < 2; i++)
                    st[t4][i] = __builtin_amdgcn_mfma_f32_16x16x32_bf16(
                        kf[t4], qf[i][1], st[t4][i], 0, 0, 0);

            // ---- causal mask: only this wave's diagonal tile ----
            if (domask && t == nwt - 1) {
                #pragma unroll
                for (int i = 0; i < 2; i++) {
                    const int qrel = 32 * (w & 1) + 16 * i + col;
                    #pragma unroll
                    for (int t4 = 0; t4 < 4; t4++) {
                        const int key0 = 16 * t4 + 4 * quad;
                        #pragma unroll
                        for (int r2 = 0; r2 < 4; r2++)
                            if (key0 + r2 > qrel) st[t4][i][r2] = -3.0e38f;
                    }
                }
            }

            // ---- softmax numerator p = exp2(s); redistribute in-register.
            // pk[t4][h] holds keys 16t4+4quad+2h+{0,1} for q=col.  Target
            // pfr[ks].u32[j] = keys 32ks+8quad+2j+{0,1}: a bit-transpose
            // (reg-bit t4_0 <-> lane-bit5, then <-> lane-bit4).
            #pragma unroll
            for (int i = 0; i < 2; i++) {
                unsigned pku[4][2];
                #pragma unroll
                for (int t4 = 0; t4 < 4; t4++) {
                    float pr[4];
                    #pragma unroll
                    for (int r2 = 0; r2 < 4; r2++) pr[r2] = fexp2(st[t4][i][r2]);
                    pku[t4][0] = pack_bf16_trunc(pr[0], pr[1]);
                    pku[t4][1] = pack_bf16_trunc(pr[2], pr[3]);
                }
                #pragma unroll
                for (int ks = 0; ks < 2; ks++)
                    #pragma unroll
                    for (int hh = 0; hh < 2; hh++)
                        pl32swap(pku[2 * ks][hh], pku[2 * ks + 1][hh]);
                #pragma unroll
                for (int ks = 0; ks < 2; ks++)
                    #pragma unroll
                    for (int hh = 0; hh < 2; hh++)
                        pl16swap(pku[2 * ks][hh], pku[2 * ks + 1][hh]);
                #pragma unroll
                for (int ks = 0; ks < 2; ks++) {
                    union { unsigned u[4]; bfrag f; } ub;
                    ub.u[0] = pku[2 * ks][0];
                    ub.u[1] = pku[2 * ks][1];
                    ub.u[2] = pku[2 * ks + 1][0];
                    ub.u[3] = pku[2 * ks + 1][1];
                    pfr[i][ks] = ub.f;
                }
            }
        }

        // BARRIER1: all waves done reading Ks[t]; V[t]'s staging loads
        // (issued after B2 of t-1, or in the prologue for t=kt0) drained.
        __syncthreads();

        // issue K[t+1] into Ks (safe: all QK^T reads of tile t complete)
        if (t + 1 < cnt) {
            const size_t ko = kArow + kt0off + (size_t)(t + 1) * 64 * E3;
            #pragma unroll
            for (int u = 0; u < 2; u++)
                gld16(qkvb + ko + (size_t)(8 * u) * E3, &Ks[16 * w + 8 * u][0]);
        }

        if (t < nwt) {
            // ---- O^T += V^T P^T ;  l += 1^T P^T ----
            #pragma unroll
            for (int ks = 0; ks < 2; ks++) {
                bfrag vf[4];
                #pragma unroll
                for (int d4 = 0; d4 < 4; d4++)
                    vf[d4] = *(const bfrag*)
                        &Vs[16 * d4 + col][(((4 * ks + quad) ^ (col & 7)) * 8)];
                #pragma unroll
                for (int d4 = 0; d4 < 4; d4++)
                    #pragma unroll
                    for (int i = 0; i < 2; i++)
                        o_[d4][i] = __builtin_amdgcn_mfma_f32_16x16x32_bf16(
                            vf[d4], pfr[i][ks], o_[d4][i], 0, 0, 0);
                #pragma unroll
                for (int i = 0; i < 2; i++)
                    ol[i] = __builtin_amdgcn_mfma_f32_16x16x32_bf16(
                        ones, pfr[i][ks], ol[i], 0, 0, 0);
            }
        }

        // BARRIER2: all waves done reading Vs[t]; K[t+1] staging drained.
        __syncthreads();

        // issue V[t+1] into Vs (safe: all PV reads of tile t complete)
        if (t + 1 < cnt) {
            const size_t vo = vArow + vt0off + (size_t)(t + 1) * 64;
            #pragma unroll
            for (int u = 0; u < 2; u++)
                gld16(vt + vo + (size_t)(8 * u) * S_LEN, &Vs[16 * w + 8 * u][0]);
        }
    }

    // ---- epilogue ----
    if (nc == 1) {
        // direct normalized write
        #pragma unroll
        for (int i = 0; i < 2; i++) {
            const float inv = 1.0f / ol[i][0];
            const int qg = q0 + 32 * w + 16 * i + col;
            #pragma unroll
            for (int d4 = 0; d4 < 4; d4++) {
                us4 pk;
                #pragma unroll
                for (int r2 = 0; r2 < 4; r2++) pk[r2] = f2bf(o_[d4][i][r2] * inv);
                *(us4*)&ctxb[(size_t)qg * EMB + h * HD + 16 * d4 + 4 * quad] = pk;
            }
        }
    } else {
        // partial write: bf16 O + fp32 l
        const int jj = (qi <= 21) ? (qi - 11) * 2 + ch : 22 + (qi - 22) * 3 + ch;
        const int slot = h * SLOTS_PER_HEAD + jj;
        u16* po = pO + (size_t)slot * (128 * 64);
        float* pl = pL + slot * 128;
        #pragma unroll
        for (int i = 0; i < 2; i++) {
            const int qrow = 32 * w + 16 * i + col;
            #pragma unroll
            for (int d4 = 0; d4 < 4; d4++) {
                us4 pk;
                #pragma unroll
                for (int r2 = 0; r2 < 4; r2++) pk[r2] = f2bf(o_[d4][i][r2]);
                *(us4*)&po[(size_t)qrow * 64 + 16 * d4 + 4 * quad] = pk;
            }
            if (quad == 0) pl[qrow] = ol[i][0];
        }
    }
}

// ---------------------------------------------------------------------------
// combine: out[q] = (sum_p O_p[q]) / (sum_p l_p[q]) over a group's 2-3 chunks.
// grid = 16 heads x 21 split q-blocks (qi 11..31) = 336.
// ---------------------------------------------------------------------------
__global__ __launch_bounds__(256)
void combine_kernel(const u16* __restrict__ pO, const float* __restrict__ pL,
                    u16* __restrict__ ctxb) {
    const int g = blockIdx.x;                  // 0..335
    const int h = g / 21, qq = g % 21;
    const int qi = 11 + qq;
    const int nc = (qi <= 21) ? 2 : 3;
    const int jj0 = (qi <= 21) ? (qi - 11) * 2 : 22 + (qi - 22) * 3;
    const int slot0 = h * SLOTS_PER_HEAD + jj0;

    const int t = threadIdx.x;
    const int q = t >> 1, dh = (t & 1) * 32;

    float l = 0.f;
    for (int p = 0; p < nc; p++) l += pL[(slot0 + p) * 128 + q];
    const float inv = 1.0f / l;

    u16* op = ctxb + (size_t)(qi * 128 + q) * EMB + h * HD + dh;

    #pragma unroll
    for (int j = 0; j < 4; j++) {
        float s[8] = {0.f, 0.f, 0.f, 0.f, 0.f, 0.f, 0.f, 0.f};
        for (int p = 0; p < nc; p++) {
            const us8 va = *(const us8*)
                (pO + ((size_t)(slot0 + p) * 128 + q) * 64 + dh + 8 * j);
            #pragma unroll
            for (int e = 0; e < 8; e++) s[e] += bf2f(va[e]);
        }
        us8 vo;
        #pragma unroll
        for (int e = 0; e < 8; e++) vo[e] = f2bf(s[e] * inv);
        *(us8*)(op + 8 * j) = vo;
    }
}

// ---------------------------------------------------------------------------
extern "C" void kernel_launch(void* const* d_in, const int* in_sizes, int n_in,
                              void* d_out, int out_size, void* d_ws, size_t ws_size,
                              hipStream_t stream) {
    const float* x      = (const float*)d_in[0];
    const float* wqkv_w = (const float*)d_in[2];
    const float* wqkv_b = (const float*)d_in[3];
    const float* out_w  = (const float*)d_in[4];
    const float* out_b  = (const float*)d_in[5];
    float* out = (float*)d_out;

    u16* qkvb = (u16*)d_ws;                        // [4096][3072] (V unused)
    u16* ctxb = qkvb + (size_t)S_LEN * E3;         // [4096][1024]
    u16* xb   = ctxb + (size_t)S_LEN * EMB;        // [4096][1024]
    u16* wt   = xb   + (size_t)S_LEN * EMB;        // [3072][1024]
    u16* owt  = wt   + (size_t)E3 * EMB;           // [1024][1024]
    u16* vtb  = owt  + (size_t)EMB * EMB;          // [16][64][4096]

    // flash partials alias the dead contiguous xb+wt span (14.68 MB):
    //   pO: 832 slots x 128x64 bf16 = 13.63 MB, pL: 832x128 f32 = 0.43 MB
    u16*   pO = xb;
    float* pL = (float*)(xb + (size_t)NSLOTS * 128 * 64);

    // RoPE table (1 MB) aliases ctxb: dead until flash writes it, read only
    // by gemm1's epilogue.
    float2* ropetab = (float2*)ctxb;

    dim3 blk(256);

    // fused preprocessing: cast + 2 transposes + rope table (1 launch)
    prep_kernel<<<dim3(3584), blk, 0, stream>>>(
        x, xb, wqkv_w, wt, out_w, owt, ropetab);

    // QKV projection + fused RoPE (+ q pre-scale) + fused V transpose
    // grid 32x24; XCD rect 8x12
    gemm_bt_kernel<1, 4, 1, 3, 8, 12>
        <<<dim3(S_LEN / 128, E3 / 128), blk, 0, stream>>>(
        xb, wt, wqkv_b, qkvb, vtb, ropetab, S_LEN, E3, EMB);

    flash16_kernel<<<dim3(1008), blk, 0, stream>>>(qkvb, vtb, ctxb, pO, pL);
    combine_kernel<<<dim3(336), blk, 0, stream>>>(pO, pL, ctxb);

    // output projection, grid 32x16; XCD rect 8x8
    gemm_bt_kernel<0, 2, 0, 2, 8, 8>
        <<<dim3(S_LEN / 128, EMB / 64), blk, 0, stream>>>(
        ctxb, owt, out_b, out, nullptr, nullptr, S_LEN, EMB, EMB);
}